// Round 1
// baseline (11835.596 us; speedup 1.0000x reference)
//
#include <hip/hip_runtime.h>

// MeshGNN: 6-layer GCN on 100k nodes / 1.6M edges, HIDDEN=128.
// out = conv_dec(relu(conv_hid^4(relu(conv_enc(x)))))
// conv(x,W,b) = segsum_dst(norm * (x@W)[src]) + b,  norm = dinv[src]*dinv[dst],
// dinv = rsqrt(deg+1) (self-loops). segsum commutes with @W:
//   encoder: aggregate x (6-wide) first, then 6->128 matmul
//   decoder: 128->3 matmul first, then 3-wide aggregate
//   hidden:  matmul 128->128, then 128-wide aggregate (atomics)

#define HID 128

__device__ __forceinline__ long long ld_idx(const void* p, long long i, int is64) {
    if (is64) return ((const long long*)p)[i];
    return (long long)((const int*)p)[i];
}

// Probe whether edge_index arrived as int64 (high 32-bit words all zero) or int32.
__global__ void detect_kernel(const unsigned int* e, long long nwords, int* flag) {
    if (threadIdx.x == 0 && blockIdx.x == 0) {
        int is64 = 1;
        long long m = nwords < 256 ? nwords : 256;
        for (long long i = 1; i < m; i += 2)
            if (e[i] != 0u) { is64 = 0; break; }
        *flag = is64;
    }
}

__global__ void deg_kernel(const void* eidx, long long E, const int* flag, float* deg) {
    long long i = (long long)blockIdx.x * blockDim.x + threadIdx.x;
    if (i >= E) return;
    int is64 = *flag;
    long long d = ld_idx(eidx, E + i, is64);
    atomicAdd(&deg[d], 1.0f);
}

__global__ void dinv_kernel(float* dinv, int N) {
    int i = blockIdx.x * blockDim.x + threadIdx.x;
    if (i >= N) return;
    dinv[i] = rsqrtf(dinv[i] + 1.0f);   // +1 self-loop; always > 0
}

// 6-wide scatter of raw x (encoder aggregation, pre-matmul)
__global__ void scatter6_kernel(const void* eidx, long long E, const int* flag,
                                const float* __restrict__ x, const float* __restrict__ dinv,
                                float* __restrict__ aggX) {
    long long i = (long long)blockIdx.x * blockDim.x + threadIdx.x;
    if (i >= E) return;
    int is64 = *flag;
    long long s = ld_idx(eidx, i, is64);
    long long d = ld_idx(eidx, E + i, is64);
    float n = dinv[s] * dinv[d];
    const float* xs = x + s * 6;
    float* o = aggX + d * 6;
#pragma unroll
    for (int c = 0; c < 6; ++c) atomicAdd(o + c, xs[c] * n);
}

// encoder: h = relu((aggX + x*dinv^2) @ W_enc + b), [N,6]@[6,128]
__global__ __launch_bounds__(256) void enc_kernel(const float* __restrict__ aggX,
                                                  const float* __restrict__ x,
                                                  const float* __restrict__ dinv,
                                                  const float* __restrict__ W,
                                                  const float* __restrict__ b,
                                                  float* __restrict__ h, int N) {
    __shared__ float Ws[6 * 128];
    __shared__ float bs[128];
    int t = threadIdx.x;
    if (t < 128) bs[t] = b[t];
    for (int i = t; i < 6 * 128; i += 256) Ws[i] = W[i];
    __syncthreads();
    long long node = (long long)blockIdx.x * 2 + (t >> 7);
    int c = t & 127;
    if (node >= N) return;
    float di = dinv[node];
    float d2 = di * di;
    float acc = bs[c];
#pragma unroll
    for (int k = 0; k < 6; ++k) {
        float rv = aggX[node * 6 + k] + x[node * 6 + k] * d2;
        acc = fmaf(rv, Ws[k * 128 + c], acc);
    }
    h[node * HID + c] = fmaxf(acc, 0.0f);
}

// [N,128] @ [128,128] fp32, W staged in LDS (64KB), 32 rows/block, 4x4 microtile
#define GM 32
__global__ __launch_bounds__(256, 2) void gemm128_kernel(const float* __restrict__ H,
                                                         const float* __restrict__ W,
                                                         float* __restrict__ O, int N) {
    __shared__ float Ws[128 * 128];
    __shared__ float Hs[GM * 128];
    int tid = threadIdx.x;
    const float4* W4 = (const float4*)W;
    float4* Ws4 = (float4*)Ws;
#pragma unroll
    for (int i = 0; i < 16; ++i) Ws4[tid + i * 256] = W4[tid + i * 256];
    long long row0 = (long long)blockIdx.x * GM;
    float4* Hs4 = (float4*)Hs;
    const float4* H4 = (const float4*)(H + row0 * HID);
#pragma unroll
    for (int i = 0; i < 4; ++i) {
        int idx = tid + i * 256;                 // float4 index; row = idx/32
        if (row0 + (idx >> 5) < N) Hs4[idx] = H4[idx];
        else Hs4[idx] = make_float4(0.f, 0.f, 0.f, 0.f);
    }
    __syncthreads();
    int tc = (tid & 31) * 4;
    int tr = (tid >> 5) * 4;
    float4 a0 = make_float4(0, 0, 0, 0), a1 = a0, a2 = a0, a3 = a0;
    for (int k = 0; k < 128; k += 4) {
        float4 w0 = *(const float4*)&Ws[(k + 0) * 128 + tc];
        float4 w1 = *(const float4*)&Ws[(k + 1) * 128 + tc];
        float4 w2 = *(const float4*)&Ws[(k + 2) * 128 + tc];
        float4 w3 = *(const float4*)&Ws[(k + 3) * 128 + tc];
#define ROWFMA(ACC, R)                                                              \
        {                                                                           \
            float4 hv = *(const float4*)&Hs[(tr + R) * 128 + k];                    \
            ACC.x += hv.x * w0.x + hv.y * w1.x + hv.z * w2.x + hv.w * w3.x;         \
            ACC.y += hv.x * w0.y + hv.y * w1.y + hv.z * w2.y + hv.w * w3.y;         \
            ACC.z += hv.x * w0.z + hv.y * w1.z + hv.z * w2.z + hv.w * w3.z;         \
            ACC.w += hv.x * w0.w + hv.y * w1.w + hv.z * w2.w + hv.w * w3.w;         \
        }
        ROWFMA(a0, 0) ROWFMA(a1, 1) ROWFMA(a2, 2) ROWFMA(a3, 3)
#undef ROWFMA
    }
    float* o = O + row0 * HID;
    if (row0 + tr + 0 < N) *(float4*)&o[(tr + 0) * 128 + tc] = a0;
    if (row0 + tr + 1 < N) *(float4*)&o[(tr + 1) * 128 + tc] = a1;
    if (row0 + tr + 2 < N) *(float4*)&o[(tr + 2) * 128 + tc] = a2;
    if (row0 + tr + 3 < N) *(float4*)&o[(tr + 3) * 128 + tc] = a3;
}

// 128-wide scatter-add: agg[dst] += tmp[src] * dinv[s]*dinv[d]; 32 lanes/edge x float4
__global__ __launch_bounds__(256) void scatter128_kernel(const void* eidx, long long E, const int* flag,
                                                         const float* __restrict__ tmp,
                                                         const float* __restrict__ dinv,
                                                         float* __restrict__ agg) {
    long long g = (long long)blockIdx.x * 8 + (threadIdx.x >> 5);
    if (g >= E) return;
    int is64 = *flag;
    int lane = threadIdx.x & 31;
    long long s = ld_idx(eidx, g, is64);
    long long d = ld_idx(eidx, E + g, is64);
    float n = dinv[s] * dinv[d];
    float4 v = *(const float4*)(tmp + s * HID + lane * 4);
    float* o = agg + d * HID + lane * 4;
    atomicAdd(o + 0, v.x * n);
    atomicAdd(o + 1, v.y * n);
    atomicAdd(o + 2, v.z * n);
    atomicAdd(o + 3, v.w * n);
}

// epilogue: h = relu(agg + tmp*dinv^2 + b)   (adds self-loop + bias, applies relu)
__global__ void post_kernel(float* __restrict__ agg, const float* __restrict__ tmp,
                            const float* __restrict__ dinv, const float* __restrict__ b,
                            long long total) {
    long long i = (long long)blockIdx.x * blockDim.x + threadIdx.x;
    if (i >= total) return;
    long long node = i >> 7;
    int c = i & 127;
    float di = dinv[node];
    float v = agg[i] + tmp[i] * di * di + b[c];
    agg[i] = fmaxf(v, 0.0f);
}

// decoder matmul: T3 = h @ W_dec, [N,128]@[128,3]
__global__ __launch_bounds__(256) void dec_kernel(const float* __restrict__ H,
                                                  const float* __restrict__ W,
                                                  float* __restrict__ T3, int N) {
    __shared__ float Ws[128 * 3];
    int t = threadIdx.x;
    for (int i = t; i < 128 * 3; i += 256) Ws[i] = W[i];
    __syncthreads();
    long long node = (long long)blockIdx.x * 256 + t;
    if (node >= N) return;
    const float* h = H + node * HID;
    float a0 = 0.f, a1 = 0.f, a2 = 0.f;
    for (int k = 0; k < 128; k += 4) {
        float4 hv = *(const float4*)&h[k];
        a0 += hv.x * Ws[(k + 0) * 3] + hv.y * Ws[(k + 1) * 3] + hv.z * Ws[(k + 2) * 3] + hv.w * Ws[(k + 3) * 3];
        a1 += hv.x * Ws[(k + 0) * 3 + 1] + hv.y * Ws[(k + 1) * 3 + 1] + hv.z * Ws[(k + 2) * 3 + 1] + hv.w * Ws[(k + 3) * 3 + 1];
        a2 += hv.x * Ws[(k + 0) * 3 + 2] + hv.y * Ws[(k + 1) * 3 + 2] + hv.z * Ws[(k + 2) * 3 + 2] + hv.w * Ws[(k + 3) * 3 + 2];
    }
    T3[node * 3 + 0] = a0;
    T3[node * 3 + 1] = a1;
    T3[node * 3 + 2] = a2;
}

__global__ void scatter3_kernel(const void* eidx, long long E, const int* flag,
                                const float* __restrict__ T3, const float* __restrict__ dinv,
                                float* __restrict__ out) {
    long long i = (long long)blockIdx.x * blockDim.x + threadIdx.x;
    if (i >= E) return;
    int is64 = *flag;
    long long s = ld_idx(eidx, i, is64);
    long long d = ld_idx(eidx, E + i, is64);
    float n = dinv[s] * dinv[d];
    const float* ts = T3 + s * 3;
    float* o = out + d * 3;
    atomicAdd(o + 0, ts[0] * n);
    atomicAdd(o + 1, ts[1] * n);
    atomicAdd(o + 2, ts[2] * n);
}

__global__ void final_kernel(float* __restrict__ out, const float* __restrict__ T3,
                             const float* __restrict__ dinv, const float* __restrict__ b,
                             int N) {
    long long i = (long long)blockIdx.x * blockDim.x + threadIdx.x;
    if (i >= (long long)N * 3) return;
    long long node = i / 3;
    int c = (int)(i % 3);
    float di = dinv[node];
    out[i] += T3[i] * di * di + b[c];
}

extern "C" void kernel_launch(void* const* d_in, const int* in_sizes, int n_in,
                              void* d_out, int out_size, void* d_ws, size_t ws_size,
                              hipStream_t stream) {
    const float* x     = (const float*)d_in[0];
    const void* eidx   = d_in[1];
    const float* W_enc = (const float*)d_in[2];
    const float* b_enc = (const float*)d_in[3];
    const float* W_hid = (const float*)d_in[4];
    const float* b_hid = (const float*)d_in[5];
    const float* W_dec = (const float*)d_in[6];
    const float* b_dec = (const float*)d_in[7];

    const int N = in_sizes[0] / 6;          // 100000
    const long long E = in_sizes[1] / 2;    // 1600000

    char* ws = (char*)d_ws;
    int* flag   = (int*)ws;
    float* dinv = (float*)(ws + 256);
    float* aggX = dinv + N;                          // N*6 floats (also reused as T3, N*3)
    float* bufA = aggX + (size_t)N * 6;              // N*128
    float* bufB = bufA + (size_t)N * HID;            // N*128

    detect_kernel<<<1, 64, 0, stream>>>((const unsigned int*)eidx, E * 2, flag);

    // degrees -> dinv
    hipMemsetAsync(dinv, 0, (size_t)N * 4, stream);
    deg_kernel<<<(int)((E + 255) / 256), 256, 0, stream>>>(eidx, E, flag, dinv);
    dinv_kernel<<<(N + 255) / 256, 256, 0, stream>>>(dinv, N);

    // encoder: aggregate x (6-wide), then matmul 6->128 (+self-loop, bias, relu)
    hipMemsetAsync(aggX, 0, (size_t)N * 6 * 4, stream);
    scatter6_kernel<<<(int)((E + 255) / 256), 256, 0, stream>>>(eidx, E, flag, x, dinv, aggX);
    enc_kernel<<<(N + 1) / 2, 256, 0, stream>>>(aggX, x, dinv, W_enc, b_enc, bufA, N);

    // 4 hidden layers
    for (int l = 0; l < 4; ++l) {
        gemm128_kernel<<<(N + GM - 1) / GM, 256, 0, stream>>>(bufA, W_hid, bufB, N);
        hipMemsetAsync(bufA, 0, (size_t)N * HID * 4, stream);
        scatter128_kernel<<<(int)((E + 7) / 8), 256, 0, stream>>>(eidx, E, flag, bufB, dinv, bufA);
        post_kernel<<<(int)(((long long)N * HID + 255) / 256), 256, 0, stream>>>(
            bufA, bufB, dinv, b_hid, (long long)N * HID);
    }

    // decoder: matmul 128->3, then 3-wide aggregate, then self-loop+bias
    dec_kernel<<<(N + 255) / 256, 256, 0, stream>>>(bufA, W_dec, aggX, N);
    hipMemsetAsync(d_out, 0, (size_t)out_size * 4, stream);
    scatter3_kernel<<<(int)((E + 255) / 256), 256, 0, stream>>>(eidx, E, flag, aggX, dinv, (float*)d_out);
    final_kernel<<<(int)(((long long)N * 3 + 255) / 256), 256, 0, stream>>>(
        (float*)d_out, aggX, dinv, b_dec, N);
}

// Round 2
// 1003.730 us; speedup vs baseline: 11.7916x; 11.7916x over previous
//
#include <hip/hip_runtime.h>

// MeshGNN: 6-layer GCN on 100k nodes / 1.6M edges, HIDDEN=128.
// Round 2: atomics -> CSR-by-dst gather. Per launch: histogram + scan + fill
// builds CSR; each conv is GEMM (epilogue-scaled by dinv) + gather (fused
// self-loop + bias + relu). No 128-wide atomics, no big memsets.

#define HID 128

__device__ __forceinline__ long long ld_idx(const void* p, long long i, int is64) {
    if (is64) return ((const long long*)p)[i];
    return (long long)((const int*)p)[i];
}

// Probe whether edge_index arrived as int64 (high 32-bit words all zero) or int32.
__global__ void detect_kernel(const unsigned int* e, long long nwords, int* flag) {
    if (threadIdx.x == 0 && blockIdx.x == 0) {
        int is64 = 1;
        long long m = nwords < 256 ? nwords : 256;
        for (long long i = 1; i < m; i += 2)
            if (e[i] != 0u) { is64 = 0; break; }
        *flag = is64;
    }
}

__global__ void hist_kernel(const void* eidx, long long E, const int* flag, int* cnt) {
    long long i = (long long)blockIdx.x * blockDim.x + threadIdx.x;
    if (i >= E) return;
    int is64 = *flag;
    int d = (int)ld_idx(eidx, E + i, is64);
    atomicAdd(&cnt[d], 1);
}

__global__ void dinv_kernel(const int* cnt, float* dinv, int N) {
    int i = blockIdx.x * blockDim.x + threadIdx.x;
    if (i >= N) return;
    dinv[i] = rsqrtf((float)cnt[i] + 1.0f);   // +1 self-loop; always > 0
}

// exclusive scan of cnt[N] -> rowptr[N], 3-kernel (block scan, scan of block sums, add)
__global__ void scan1_kernel(const int* cnt, int* rowptr, int* bsum, int N) {
    __shared__ int s[256];
    int i = blockIdx.x * 256 + threadIdx.x;
    int v = (i < N) ? cnt[i] : 0;
    s[threadIdx.x] = v;
    __syncthreads();
    for (int off = 1; off < 256; off <<= 1) {
        int t = (threadIdx.x >= off) ? s[threadIdx.x - off] : 0;
        __syncthreads();
        s[threadIdx.x] += t;
        __syncthreads();
    }
    if (i < N) rowptr[i] = s[threadIdx.x] - v;   // exclusive
    if (threadIdx.x == 255) bsum[blockIdx.x] = s[255];
}

__global__ void scan2_kernel(int* bsum, int nb) {
    __shared__ int s[512];
    int t = threadIdx.x;
    int v = (t < nb) ? bsum[t] : 0;
    s[t] = v;
    __syncthreads();
    for (int off = 1; off < 512; off <<= 1) {
        int u = (t >= off) ? s[t - off] : 0;
        __syncthreads();
        s[t] += u;
        __syncthreads();
    }
    if (t < nb) bsum[t] = s[t] - v;   // exclusive block offsets
}

__global__ void scan3_kernel(int* rowptr, const int* bsum, int N, long long E) {
    int i = blockIdx.x * 256 + threadIdx.x;
    if (i < N) rowptr[i] += bsum[blockIdx.x];
    if (i == 0) rowptr[N] = (int)E;
}

__global__ void fill_kernel(const void* eidx, long long E, const int* flag,
                            const int* __restrict__ rowptr, int* __restrict__ cursor,
                            int* __restrict__ csr) {
    long long i = (long long)blockIdx.x * blockDim.x + threadIdx.x;
    if (i >= E) return;
    int is64 = *flag;
    int s = (int)ld_idx(eidx, i, is64);
    int d = (int)ld_idx(eidx, E + i, is64);
    int pos = rowptr[d] + atomicAdd(&cursor[d], 1);
    csr[pos] = s;
}

// encoder aggregation (6-wide), thread per dst:
// aggV[dst] = dinv[dst] * ( sum_src x[src]*dinv[src] + x[dst]*dinv[dst] )
__global__ void gather6_kernel(const int* __restrict__ rowptr, const int* __restrict__ csr,
                               const float* __restrict__ x, const float* __restrict__ dinv,
                               float* __restrict__ aggV, int N) {
    int i = blockIdx.x * blockDim.x + threadIdx.x;
    if (i >= N) return;
    int s = rowptr[i], e = rowptr[i + 1];
    float di = dinv[i];
    const float* xi = x + (long long)i * 6;
    float a0 = xi[0] * di, a1 = xi[1] * di, a2 = xi[2] * di;
    float a3 = xi[3] * di, a4 = xi[4] * di, a5 = xi[5] * di;
    for (int j = s; j < e; ++j) {
        int src = csr[j];
        float ds = dinv[src];
        const float* xs = x + (long long)src * 6;
        a0 += xs[0] * ds; a1 += xs[1] * ds; a2 += xs[2] * ds;
        a3 += xs[3] * ds; a4 += xs[4] * ds; a5 += xs[5] * ds;
    }
    float* o = aggV + (long long)i * 6;
    o[0] = a0 * di; o[1] = a1 * di; o[2] = a2 * di;
    o[3] = a3 * di; o[4] = a4 * di; o[5] = a5 * di;
}

// encoder matmul: h = relu(aggV @ W_enc + b), [N,6]@[6,128]
__global__ __launch_bounds__(256) void enc_kernel(const float* __restrict__ aggV,
                                                  const float* __restrict__ W,
                                                  const float* __restrict__ b,
                                                  float* __restrict__ h, int N) {
    __shared__ float Ws[6 * 128];
    __shared__ float bs[128];
    int t = threadIdx.x;
    if (t < 128) bs[t] = b[t];
    for (int i = t; i < 6 * 128; i += 256) Ws[i] = W[i];
    __syncthreads();
    long long node = (long long)blockIdx.x * 2 + (t >> 7);
    int c = t & 127;
    if (node >= N) return;
    float acc = bs[c];
#pragma unroll
    for (int k = 0; k < 6; ++k)
        acc = fmaf(aggV[node * 6 + k], Ws[k * 128 + c], acc);
    h[node * HID + c] = fmaxf(acc, 0.0f);
}

// [N,128] @ [128,128] fp32, W in LDS; epilogue scales by dinv[row]: G = (H@W)*dinv
#define GM 32
__global__ __launch_bounds__(256, 2) void gemm128_kernel(const float* __restrict__ H,
                                                         const float* __restrict__ W,
                                                         const float* __restrict__ dinv,
                                                         float* __restrict__ G, int N) {
    __shared__ float Ws[128 * 128];
    __shared__ float Hs[GM * 128];
    int tid = threadIdx.x;
    const float4* W4 = (const float4*)W;
    float4* Ws4 = (float4*)Ws;
#pragma unroll
    for (int i = 0; i < 16; ++i) Ws4[tid + i * 256] = W4[tid + i * 256];
    long long row0 = (long long)blockIdx.x * GM;
    float4* Hs4 = (float4*)Hs;
    const float4* H4 = (const float4*)(H + row0 * HID);
#pragma unroll
    for (int i = 0; i < 4; ++i) {
        int idx = tid + i * 256;                 // float4 index; row = idx/32
        if (row0 + (idx >> 5) < N) Hs4[idx] = H4[idx];
        else Hs4[idx] = make_float4(0.f, 0.f, 0.f, 0.f);
    }
    __syncthreads();
    int tc = (tid & 31) * 4;
    int tr = (tid >> 5) * 4;
    float4 a0 = make_float4(0, 0, 0, 0), a1 = a0, a2 = a0, a3 = a0;
    for (int k = 0; k < 128; k += 4) {
        float4 w0 = *(const float4*)&Ws[(k + 0) * 128 + tc];
        float4 w1 = *(const float4*)&Ws[(k + 1) * 128 + tc];
        float4 w2 = *(const float4*)&Ws[(k + 2) * 128 + tc];
        float4 w3 = *(const float4*)&Ws[(k + 3) * 128 + tc];
#define ROWFMA(ACC, R)                                                              \
        {                                                                           \
            float4 hv = *(const float4*)&Hs[(tr + R) * 128 + k];                    \
            ACC.x += hv.x * w0.x + hv.y * w1.x + hv.z * w2.x + hv.w * w3.x;         \
            ACC.y += hv.x * w0.y + hv.y * w1.y + hv.z * w2.y + hv.w * w3.y;         \
            ACC.z += hv.x * w0.z + hv.y * w1.z + hv.z * w2.z + hv.w * w3.z;         \
            ACC.w += hv.x * w0.w + hv.y * w1.w + hv.z * w2.w + hv.w * w3.w;         \
        }
        ROWFMA(a0, 0) ROWFMA(a1, 1) ROWFMA(a2, 2) ROWFMA(a3, 3)
#undef ROWFMA
    }
    float* o = G + row0 * HID;
#define STORE(ACC, R)                                                               \
        if (row0 + tr + R < N) {                                                    \
            float di = dinv[row0 + tr + R];                                         \
            ACC.x *= di; ACC.y *= di; ACC.z *= di; ACC.w *= di;                     \
            *(float4*)&o[(tr + R) * 128 + tc] = ACC;                                \
        }
    STORE(a0, 0) STORE(a1, 1) STORE(a2, 2) STORE(a3, 3)
#undef STORE
}

// hidden aggregation: 32 lanes per dst node, float4 per lane.
// H[dst] = relu( dinv[dst]*(sum_src G[src] + G[dst]) + b )
__global__ __launch_bounds__(256) void gather128_kernel(const int* __restrict__ rowptr,
                                                        const int* __restrict__ csr,
                                                        const float* __restrict__ G,
                                                        const float* __restrict__ dinv,
                                                        const float* __restrict__ b,
                                                        float* __restrict__ H, int N) {
    int grp = blockIdx.x * 8 + (threadIdx.x >> 5);
    if (grp >= N) return;
    int lane = threadIdx.x & 31;
    int s = rowptr[grp], e = rowptr[grp + 1];
    const float4* G4 = (const float4*)G;
    float4 acc = G4[(long long)grp * 32 + lane];   // self term
    int j = s;
    for (; j + 3 < e; j += 4) {
        int s0 = csr[j], s1 = csr[j + 1], s2 = csr[j + 2], s3 = csr[j + 3];
        float4 v0 = G4[(long long)s0 * 32 + lane];
        float4 v1 = G4[(long long)s1 * 32 + lane];
        float4 v2 = G4[(long long)s2 * 32 + lane];
        float4 v3 = G4[(long long)s3 * 32 + lane];
        acc.x += v0.x + v1.x + v2.x + v3.x;
        acc.y += v0.y + v1.y + v2.y + v3.y;
        acc.z += v0.z + v1.z + v2.z + v3.z;
        acc.w += v0.w + v1.w + v2.w + v3.w;
    }
    for (; j < e; ++j) {
        int s0 = csr[j];
        float4 v = G4[(long long)s0 * 32 + lane];
        acc.x += v.x; acc.y += v.y; acc.z += v.z; acc.w += v.w;
    }
    float di = dinv[grp];
    float4 bb = *(const float4*)&b[lane * 4];
    float4 r;
    r.x = fmaxf(fmaf(acc.x, di, bb.x), 0.0f);
    r.y = fmaxf(fmaf(acc.y, di, bb.y), 0.0f);
    r.z = fmaxf(fmaf(acc.z, di, bb.z), 0.0f);
    r.w = fmaxf(fmaf(acc.w, di, bb.w), 0.0f);
    ((float4*)H)[(long long)grp * 32 + lane] = r;
}

// decoder matmul: T3g = (h @ W_dec) * dinv[row], [N,128]@[128,3]
__global__ __launch_bounds__(256) void dec_kernel(const float* __restrict__ H,
                                                  const float* __restrict__ W,
                                                  const float* __restrict__ dinv,
                                                  float* __restrict__ T3g, int N) {
    __shared__ float Ws[128 * 3];
    int t = threadIdx.x;
    for (int i = t; i < 128 * 3; i += 256) Ws[i] = W[i];
    __syncthreads();
    long long node = (long long)blockIdx.x * 256 + t;
    if (node >= N) return;
    const float* h = H + node * HID;
    float a0 = 0.f, a1 = 0.f, a2 = 0.f;
    for (int k = 0; k < 128; k += 4) {
        float4 hv = *(const float4*)&h[k];
        a0 += hv.x * Ws[(k + 0) * 3] + hv.y * Ws[(k + 1) * 3] + hv.z * Ws[(k + 2) * 3] + hv.w * Ws[(k + 3) * 3];
        a1 += hv.x * Ws[(k + 0) * 3 + 1] + hv.y * Ws[(k + 1) * 3 + 1] + hv.z * Ws[(k + 2) * 3 + 1] + hv.w * Ws[(k + 3) * 3 + 1];
        a2 += hv.x * Ws[(k + 0) * 3 + 2] + hv.y * Ws[(k + 1) * 3 + 2] + hv.z * Ws[(k + 2) * 3 + 2] + hv.w * Ws[(k + 3) * 3 + 2];
    }
    float di = dinv[node];
    T3g[node * 3 + 0] = a0 * di;
    T3g[node * 3 + 1] = a1 * di;
    T3g[node * 3 + 2] = a2 * di;
}

// decoder aggregation (3-wide), thread per dst: out = dinv*(sum + self) + b
__global__ void gather3_kernel(const int* __restrict__ rowptr, const int* __restrict__ csr,
                               const float* __restrict__ T3g, const float* __restrict__ dinv,
                               const float* __restrict__ b, float* __restrict__ out, int N) {
    int i = blockIdx.x * blockDim.x + threadIdx.x;
    if (i >= N) return;
    int s = rowptr[i], e = rowptr[i + 1];
    const float* ti = T3g + (long long)i * 3;
    float a0 = ti[0], a1 = ti[1], a2 = ti[2];   // self
    for (int j = s; j < e; ++j) {
        int src = csr[j];
        const float* ts = T3g + (long long)src * 3;
        a0 += ts[0]; a1 += ts[1]; a2 += ts[2];
    }
    float di = dinv[i];
    float* o = out + (long long)i * 3;
    o[0] = fmaf(a0, di, b[0]);
    o[1] = fmaf(a1, di, b[1]);
    o[2] = fmaf(a2, di, b[2]);
}

extern "C" void kernel_launch(void* const* d_in, const int* in_sizes, int n_in,
                              void* d_out, int out_size, void* d_ws, size_t ws_size,
                              hipStream_t stream) {
    const float* x     = (const float*)d_in[0];
    const void* eidx   = d_in[1];
    const float* W_enc = (const float*)d_in[2];
    const float* b_enc = (const float*)d_in[3];
    const float* W_hid = (const float*)d_in[4];
    const float* b_hid = (const float*)d_in[5];
    const float* W_dec = (const float*)d_in[6];
    const float* b_dec = (const float*)d_in[7];

    const int N = in_sizes[0] / 6;          // 100000
    const long long E = in_sizes[1] / 2;    // 1600000
    const int NBLK = (N + 255) / 256;       // 391 (<= 512 for scan2)

    char* ws = (char*)d_ws;
    size_t off = 0;
    auto alloc = [&](size_t bytes) { char* p = ws + off; off += (bytes + 255) & ~(size_t)255; return p; };
    int*   flag   = (int*)alloc(4);
    float* dinv   = (float*)alloc((size_t)N * 4);
    int*   cnt    = (int*)alloc((size_t)N * 4);        // histogram, then cursor
    int*   rowptr = (int*)alloc(((size_t)N + 1) * 4);
    int*   bsum   = (int*)alloc(2048 * 4);
    int*   csr    = (int*)alloc((size_t)E * 4);
    float* aggV   = (float*)alloc((size_t)N * 6 * 4);  // encoder agg; reused as T3g
    float* bufA   = (float*)alloc((size_t)N * HID * 4);
    float* bufB   = (float*)alloc((size_t)N * HID * 4);

    detect_kernel<<<1, 64, 0, stream>>>((const unsigned int*)eidx, E * 2, flag);

    // CSR build: histogram -> dinv -> exclusive scan -> fill
    hipMemsetAsync(cnt, 0, (size_t)N * 4, stream);
    hist_kernel<<<(int)((E + 255) / 256), 256, 0, stream>>>(eidx, E, flag, cnt);
    dinv_kernel<<<NBLK, 256, 0, stream>>>(cnt, dinv, N);
    scan1_kernel<<<NBLK, 256, 0, stream>>>(cnt, rowptr, bsum, N);
    scan2_kernel<<<1, 512, 0, stream>>>(bsum, NBLK);
    scan3_kernel<<<NBLK, 256, 0, stream>>>(rowptr, bsum, N, E);
    hipMemsetAsync(cnt, 0, (size_t)N * 4, stream);     // cursor
    fill_kernel<<<(int)((E + 255) / 256), 256, 0, stream>>>(eidx, E, flag, rowptr, cnt, csr);

    // encoder
    gather6_kernel<<<NBLK, 256, 0, stream>>>(rowptr, csr, x, dinv, aggV, N);
    enc_kernel<<<(N + 1) / 2, 256, 0, stream>>>(aggV, W_enc, b_enc, bufA, N);

    // 4 hidden layers
    for (int l = 0; l < 4; ++l) {
        gemm128_kernel<<<(N + GM - 1) / GM, 256, 0, stream>>>(bufA, W_hid, dinv, bufB, N);
        gather128_kernel<<<(N + 7) / 8, 256, 0, stream>>>(rowptr, csr, bufB, dinv, b_hid, bufA, N);
    }

    // decoder
    dec_kernel<<<(N + 255) / 256, 256, 0, stream>>>(bufA, W_dec, dinv, aggV, N);
    gather3_kernel<<<NBLK, 256, 0, stream>>>(rowptr, csr, aggV, dinv, b_dec, (float*)d_out, N);
}

// Round 3
// 830.922 us; speedup vs baseline: 14.2439x; 1.2080x over previous
//
#include <hip/hip_runtime.h>

// MeshGNN: 6-layer GCN on 100k nodes / 1.6M edges, HIDDEN=128.
// Round 3: (a) CSR build via rank-trick (one atomic pass instead of two),
// (b) hidden GEMM via split-bf16 MFMA (hi+lo planes, 3 MFMAs ~ fp32 accuracy),
// W pre-fragmented per launch, H split into XOR-swizzled LDS.
// Gather (dominant, L3-bound) left unchanged to isolate deltas.

#define HID 128

typedef __attribute__((ext_vector_type(4))) float f32x4;
typedef __attribute__((ext_vector_type(8))) short bf16x8;

__device__ __forceinline__ long long ld_idx(const void* p, long long i, int is64) {
    if (is64) return ((const long long*)p)[i];
    return (long long)((const int*)p)[i];
}

__device__ __forceinline__ unsigned short f2bf(float v) {
    unsigned u = __float_as_uint(v);
    unsigned r = (u + 0x7fffu + ((u >> 16) & 1u)) >> 16;
    return (unsigned short)r;
}
__device__ __forceinline__ float bf2f(unsigned short h) {
    return __uint_as_float(((unsigned)h) << 16);
}

// Probe whether edge_index arrived as int64 (high 32-bit words all zero) or int32.
__global__ void detect_kernel(const unsigned int* e, long long nwords, int* flag) {
    if (threadIdx.x == 0 && blockIdx.x == 0) {
        int is64 = 1;
        long long m = nwords < 256 ? nwords : 256;
        for (long long i = 1; i < m; i += 2)
            if (e[i] != 0u) { is64 = 0; break; }
        *flag = is64;
    }
}

// pass A: histogram + per-edge rank (single atomic pass)
__global__ void rank_kernel(const void* eidx, long long E, const int* flag,
                            int* __restrict__ cnt, int* __restrict__ rank) {
    long long i = (long long)blockIdx.x * blockDim.x + threadIdx.x;
    if (i >= E) return;
    int is64 = *flag;
    int d = (int)ld_idx(eidx, E + i, is64);
    rank[i] = atomicAdd(&cnt[d], 1);
}

__global__ void dinv_kernel(const int* cnt, float* dinv, int N) {
    int i = blockIdx.x * blockDim.x + threadIdx.x;
    if (i >= N) return;
    dinv[i] = rsqrtf((float)cnt[i] + 1.0f);   // +1 self-loop; always > 0
}

// exclusive scan of cnt[N] -> rowptr[N], 3-kernel
__global__ void scan1_kernel(const int* cnt, int* rowptr, int* bsum, int N) {
    __shared__ int s[256];
    int i = blockIdx.x * 256 + threadIdx.x;
    int v = (i < N) ? cnt[i] : 0;
    s[threadIdx.x] = v;
    __syncthreads();
    for (int off = 1; off < 256; off <<= 1) {
        int t = (threadIdx.x >= off) ? s[threadIdx.x - off] : 0;
        __syncthreads();
        s[threadIdx.x] += t;
        __syncthreads();
    }
    if (i < N) rowptr[i] = s[threadIdx.x] - v;   // exclusive
    if (threadIdx.x == 255) bsum[blockIdx.x] = s[255];
}

__global__ void scan2_kernel(int* bsum, int nb) {
    __shared__ int s[512];
    int t = threadIdx.x;
    int v = (t < nb) ? bsum[t] : 0;
    s[t] = v;
    __syncthreads();
    for (int off = 1; off < 512; off <<= 1) {
        int u = (t >= off) ? s[t - off] : 0;
        __syncthreads();
        s[t] += u;
        __syncthreads();
    }
    if (t < nb) bsum[t] = s[t] - v;   // exclusive block offsets
}

__global__ void scan3_kernel(int* rowptr, const int* bsum, int N, long long E) {
    int i = blockIdx.x * 256 + threadIdx.x;
    if (i < N) rowptr[i] += bsum[blockIdx.x];
    if (i == 0) rowptr[N] = (int)E;
}

// pass B: scatter src into CSR slot (no atomics)
__global__ void fill2_kernel(const void* eidx, long long E, const int* flag,
                             const int* __restrict__ rowptr, const int* __restrict__ rank,
                             int* __restrict__ csr) {
    long long i = (long long)blockIdx.x * blockDim.x + threadIdx.x;
    if (i >= E) return;
    int is64 = *flag;
    int s = (int)ld_idx(eidx, i, is64);
    int d = (int)ld_idx(eidx, E + i, is64);
    csr[rowptr[d] + rank[i]] = s;
}

// encoder aggregation (6-wide), thread per dst
__global__ void gather6_kernel(const int* __restrict__ rowptr, const int* __restrict__ csr,
                               const float* __restrict__ x, const float* __restrict__ dinv,
                               float* __restrict__ aggV, int N) {
    int i = blockIdx.x * blockDim.x + threadIdx.x;
    if (i >= N) return;
    int s = rowptr[i], e = rowptr[i + 1];
    float di = dinv[i];
    const float* xi = x + (long long)i * 6;
    float a0 = xi[0] * di, a1 = xi[1] * di, a2 = xi[2] * di;
    float a3 = xi[3] * di, a4 = xi[4] * di, a5 = xi[5] * di;
    for (int j = s; j < e; ++j) {
        int src = csr[j];
        float ds = dinv[src];
        const float* xs = x + (long long)src * 6;
        a0 += xs[0] * ds; a1 += xs[1] * ds; a2 += xs[2] * ds;
        a3 += xs[3] * ds; a4 += xs[4] * ds; a5 += xs[5] * ds;
    }
    float* o = aggV + (long long)i * 6;
    o[0] = a0 * di; o[1] = a1 * di; o[2] = a2 * di;
    o[3] = a3 * di; o[4] = a4 * di; o[5] = a5 * di;
}

// encoder matmul: h = relu(aggV @ W_enc + b), [N,6]@[6,128]
__global__ __launch_bounds__(256) void enc_kernel(const float* __restrict__ aggV,
                                                  const float* __restrict__ W,
                                                  const float* __restrict__ b,
                                                  float* __restrict__ h, int N) {
    __shared__ float Ws[6 * 128];
    __shared__ float bs[128];
    int t = threadIdx.x;
    if (t < 128) bs[t] = b[t];
    for (int i = t; i < 6 * 128; i += 256) Ws[i] = W[i];
    __syncthreads();
    long long node = (long long)blockIdx.x * 2 + (t >> 7);
    int c = t & 127;
    if (node >= N) return;
    float acc = bs[c];
#pragma unroll
    for (int k = 0; k < 6; ++k)
        acc = fmaf(aggV[node * 6 + k], Ws[k * 128 + c], acc);
    h[node * HID + c] = fmaxf(acc, 0.0f);
}

// W_hid -> fragment-ordered split-bf16: Wf[plane][nt][ks][lane][j]
// c = nt*16+(lane&15), k = ks*32+(lane>>4)*8+j, plane stride 16384
__global__ void wprep_kernel(const float* __restrict__ W, unsigned short* __restrict__ Wf) {
    int idx = blockIdx.x * 256 + threadIdx.x;
    if (idx >= 16384) return;
    int j = idx & 7;
    int lane = (idx >> 3) & 63;
    int ks = (idx >> 9) & 3;
    int nt = idx >> 11;
    int c = (nt << 4) + (lane & 15);
    int k = (ks << 5) + ((lane >> 4) << 3) + j;
    float v = W[k * 128 + c];
    unsigned short hi = f2bf(v);
    unsigned short lo = f2bf(v - bf2f(hi));
    Wf[idx] = hi;
    Wf[idx + 16384] = lo;
}

// hidden GEMM: G = (H @ W_hid) * dinv[row], split-bf16 MFMA (hi*hi+hi*lo+lo*hi).
// Block: 256 thr = 4 waves, M-tile 32 rows, N=128. Wave w: msub=w&1 (16 rows),
// nh=w>>1 (64 cols = 4 N-tiles). A staged in LDS hi/lo, XOR-swizzled 16B slots.
__global__ __launch_bounds__(256) void gemm_mfma_kernel(const float* __restrict__ H,
                                                        const unsigned short* __restrict__ Wf,
                                                        const float* __restrict__ dinv,
                                                        float* __restrict__ G, int N) {
    __shared__ unsigned short Ahi[32 * 128];
    __shared__ unsigned short Alo[32 * 128];
    int tid = threadIdx.x;
    long long row0 = (long long)blockIdx.x * 32;
    const float4* H4 = (const float4*)(H + row0 * HID);
#pragma unroll
    for (int i = 0; i < 4; ++i) {
        int idx = tid + i * 256;              // float4 index, 1024 total
        int row = idx >> 5;                   // 0..31
        int k0 = (idx & 31) << 2;             // 0,4,...,124
        float4 v = make_float4(0.f, 0.f, 0.f, 0.f);
        if (row0 + row < N) v = H4[idx];
        unsigned short h0 = f2bf(v.x), h1 = f2bf(v.y), h2 = f2bf(v.z), h3 = f2bf(v.w);
        unsigned short l0 = f2bf(v.x - bf2f(h0));
        unsigned short l1 = f2bf(v.y - bf2f(h1));
        unsigned short l2 = f2bf(v.z - bf2f(h2));
        unsigned short l3 = f2bf(v.w - bf2f(h3));
        // swizzle: 16B slot index (k0>>3) XOR (row&7)
        int sw = row * 128 + ((((k0 >> 3) ^ (row & 7)) << 3) | (k0 & 7));
        *(uint2*)&Ahi[sw] = make_uint2((unsigned)h0 | ((unsigned)h1 << 16),
                                       (unsigned)h2 | ((unsigned)h3 << 16));
        *(uint2*)&Alo[sw] = make_uint2((unsigned)l0 | ((unsigned)l1 << 16),
                                       (unsigned)l2 | ((unsigned)l3 << 16));
    }
    __syncthreads();
    int w = tid >> 6, lane = tid & 63;
    int msub = w & 1, nh = w >> 1;
    int arow = (msub << 4) + (lane & 15);
    int abase = arow * 128;
    f32x4 acc[4] = {};
    const bf16x8* Bf = (const bf16x8*)Wf;
#pragma unroll
    for (int ks = 0; ks < 4; ++ks) {
        int slot = (ks << 2) + (lane >> 4);
        int aoff = abase + ((slot ^ (arow & 7)) << 3);
        bf16x8 ah = *(const bf16x8*)&Ahi[aoff];
        bf16x8 al = *(const bf16x8*)&Alo[aoff];
#pragma unroll
        for (int t = 0; t < 4; ++t) {
            int g = ((((nh * 4 + t) << 2) + ks) << 6) + lane;
            bf16x8 bh = Bf[g];
            bf16x8 bl = Bf[g + 2048];
            acc[t] = __builtin_amdgcn_mfma_f32_16x16x32_bf16(ah, bh, acc[t], 0, 0, 0);
            acc[t] = __builtin_amdgcn_mfma_f32_16x16x32_bf16(ah, bl, acc[t], 0, 0, 0);
            acc[t] = __builtin_amdgcn_mfma_f32_16x16x32_bf16(al, bh, acc[t], 0, 0, 0);
        }
    }
    // C/D: col = lane&15 (+tile), row = (lane>>4)*4 + reg (+msub*16)
    int rbase = (msub << 4) + ((lane >> 4) << 2);
    int cbase = (nh << 6) + (lane & 15);
#pragma unroll
    for (int t = 0; t < 4; ++t) {
        int col = cbase + (t << 4);
#pragma unroll
        for (int r = 0; r < 4; ++r) {
            long long grow = row0 + rbase + r;
            if (grow < N) G[grow * HID + col] = acc[t][r] * dinv[grow];
        }
    }
}

// hidden aggregation: 32 lanes per dst node, float4 per lane.
// H[dst] = relu( dinv[dst]*(sum_src G[src] + G[dst]) + b )
__global__ __launch_bounds__(256) void gather128_kernel(const int* __restrict__ rowptr,
                                                        const int* __restrict__ csr,
                                                        const float* __restrict__ G,
                                                        const float* __restrict__ dinv,
                                                        const float* __restrict__ b,
                                                        float* __restrict__ H, int N) {
    int grp = blockIdx.x * 8 + (threadIdx.x >> 5);
    if (grp >= N) return;
    int lane = threadIdx.x & 31;
    int s = rowptr[grp], e = rowptr[grp + 1];
    const float4* G4 = (const float4*)G;
    float4 acc = G4[(long long)grp * 32 + lane];   // self term
    int j = s;
    for (; j + 3 < e; j += 4) {
        int s0 = csr[j], s1 = csr[j + 1], s2 = csr[j + 2], s3 = csr[j + 3];
        float4 v0 = G4[(long long)s0 * 32 + lane];
        float4 v1 = G4[(long long)s1 * 32 + lane];
        float4 v2 = G4[(long long)s2 * 32 + lane];
        float4 v3 = G4[(long long)s3 * 32 + lane];
        acc.x += v0.x + v1.x + v2.x + v3.x;
        acc.y += v0.y + v1.y + v2.y + v3.y;
        acc.z += v0.z + v1.z + v2.z + v3.z;
        acc.w += v0.w + v1.w + v2.w + v3.w;
    }
    for (; j < e; ++j) {
        int s0 = csr[j];
        float4 v = G4[(long long)s0 * 32 + lane];
        acc.x += v.x; acc.y += v.y; acc.z += v.z; acc.w += v.w;
    }
    float di = dinv[grp];
    float4 bb = *(const float4*)&b[lane * 4];
    float4 r;
    r.x = fmaxf(fmaf(acc.x, di, bb.x), 0.0f);
    r.y = fmaxf(fmaf(acc.y, di, bb.y), 0.0f);
    r.z = fmaxf(fmaf(acc.z, di, bb.z), 0.0f);
    r.w = fmaxf(fmaf(acc.w, di, bb.w), 0.0f);
    ((float4*)H)[(long long)grp * 32 + lane] = r;
}

// decoder matmul: T3g = (h @ W_dec) * dinv[row], [N,128]@[128,3]
__global__ __launch_bounds__(256) void dec_kernel(const float* __restrict__ H,
                                                  const float* __restrict__ W,
                                                  const float* __restrict__ dinv,
                                                  float* __restrict__ T3g, int N) {
    __shared__ float Ws[128 * 3];
    int t = threadIdx.x;
    for (int i = t; i < 128 * 3; i += 256) Ws[i] = W[i];
    __syncthreads();
    long long node = (long long)blockIdx.x * 256 + t;
    if (node >= N) return;
    const float* h = H + node * HID;
    float a0 = 0.f, a1 = 0.f, a2 = 0.f;
    for (int k = 0; k < 128; k += 4) {
        float4 hv = *(const float4*)&h[k];
        a0 += hv.x * Ws[(k + 0) * 3] + hv.y * Ws[(k + 1) * 3] + hv.z * Ws[(k + 2) * 3] + hv.w * Ws[(k + 3) * 3];
        a1 += hv.x * Ws[(k + 0) * 3 + 1] + hv.y * Ws[(k + 1) * 3 + 1] + hv.z * Ws[(k + 2) * 3 + 1] + hv.w * Ws[(k + 3) * 3 + 1];
        a2 += hv.x * Ws[(k + 0) * 3 + 2] + hv.y * Ws[(k + 1) * 3 + 2] + hv.z * Ws[(k + 2) * 3 + 2] + hv.w * Ws[(k + 3) * 3 + 2];
    }
    float di = dinv[node];
    T3g[node * 3 + 0] = a0 * di;
    T3g[node * 3 + 1] = a1 * di;
    T3g[node * 3 + 2] = a2 * di;
}

// decoder aggregation (3-wide), thread per dst: out = dinv*(sum + self) + b
__global__ void gather3_kernel(const int* __restrict__ rowptr, const int* __restrict__ csr,
                               const float* __restrict__ T3g, const float* __restrict__ dinv,
                               const float* __restrict__ b, float* __restrict__ out, int N) {
    int i = blockIdx.x * blockDim.x + threadIdx.x;
    if (i >= N) return;
    int s = rowptr[i], e = rowptr[i + 1];
    const float* ti = T3g + (long long)i * 3;
    float a0 = ti[0], a1 = ti[1], a2 = ti[2];   // self
    for (int j = s; j < e; ++j) {
        int src = csr[j];
        const float* ts = T3g + (long long)src * 3;
        a0 += ts[0]; a1 += ts[1]; a2 += ts[2];
    }
    float di = dinv[i];
    float* o = out + (long long)i * 3;
    o[0] = fmaf(a0, di, b[0]);
    o[1] = fmaf(a1, di, b[1]);
    o[2] = fmaf(a2, di, b[2]);
}

extern "C" void kernel_launch(void* const* d_in, const int* in_sizes, int n_in,
                              void* d_out, int out_size, void* d_ws, size_t ws_size,
                              hipStream_t stream) {
    const float* x     = (const float*)d_in[0];
    const void* eidx   = d_in[1];
    const float* W_enc = (const float*)d_in[2];
    const float* b_enc = (const float*)d_in[3];
    const float* W_hid = (const float*)d_in[4];
    const float* b_hid = (const float*)d_in[5];
    const float* W_dec = (const float*)d_in[6];
    const float* b_dec = (const float*)d_in[7];

    const int N = in_sizes[0] / 6;          // 100000
    const long long E = in_sizes[1] / 2;    // 1600000
    const int NBLK = (N + 255) / 256;       // 391 (<= 512 for scan2)

    char* ws = (char*)d_ws;
    size_t off = 0;
    auto alloc = [&](size_t bytes) { char* p = ws + off; off += (bytes + 255) & ~(size_t)255; return p; };
    int*            flag   = (int*)alloc(4);
    float*          dinv   = (float*)alloc((size_t)N * 4);
    int*            cnt    = (int*)alloc((size_t)N * 4);
    int*            rowptr = (int*)alloc(((size_t)N + 1) * 4);
    int*            bsum   = (int*)alloc(2048 * 4);
    unsigned short* Wf     = (unsigned short*)alloc(2 * 16384 * 2);
    int*            csr    = (int*)alloc((size_t)E * 4);
    int*            rank   = (int*)alloc((size_t)E * 4);
    float*          aggV   = (float*)alloc((size_t)N * 6 * 4);   // encoder agg; reused as T3g
    float*          bufA   = (float*)alloc((size_t)N * HID * 4);
    float*          bufB   = (float*)alloc((size_t)N * HID * 4);

    detect_kernel<<<1, 64, 0, stream>>>((const unsigned int*)eidx, E * 2, flag);

    // CSR build: rank pass (histogram + ranks) -> dinv -> scan -> non-atomic fill
    hipMemsetAsync(cnt, 0, (size_t)N * 4, stream);
    rank_kernel<<<(int)((E + 255) / 256), 256, 0, stream>>>(eidx, E, flag, cnt, rank);
    dinv_kernel<<<NBLK, 256, 0, stream>>>(cnt, dinv, N);
    scan1_kernel<<<NBLK, 256, 0, stream>>>(cnt, rowptr, bsum, N);
    scan2_kernel<<<1, 512, 0, stream>>>(bsum, NBLK);
    scan3_kernel<<<NBLK, 256, 0, stream>>>(rowptr, bsum, N, E);
    fill2_kernel<<<(int)((E + 255) / 256), 256, 0, stream>>>(eidx, E, flag, rowptr, rank, csr);

    // W_hid fragment prep
    wprep_kernel<<<64, 256, 0, stream>>>(W_hid, Wf);

    // encoder
    gather6_kernel<<<NBLK, 256, 0, stream>>>(rowptr, csr, x, dinv, aggV, N);
    enc_kernel<<<(N + 1) / 2, 256, 0, stream>>>(aggV, W_enc, b_enc, bufA, N);

    // 4 hidden layers: MFMA GEMM + gather
    for (int l = 0; l < 4; ++l) {
        gemm_mfma_kernel<<<(N + 31) / 32, 256, 0, stream>>>(bufA, Wf, dinv, bufB, N);
        gather128_kernel<<<(N + 7) / 8, 256, 0, stream>>>(rowptr, csr, bufB, dinv, b_hid, bufA, N);
    }

    // decoder
    dec_kernel<<<(N + 255) / 256, 256, 0, stream>>>(bufA, W_dec, dinv, aggV, N);
    gather3_kernel<<<NBLK, 256, 0, stream>>>(rowptr, csr, aggV, dinv, b_dec, (float*)d_out, N);
}

// Round 4
// 824.466 us; speedup vs baseline: 14.3555x; 1.0078x over previous
//
#include <hip/hip_runtime.h>

// MeshGNN: 6-layer GCN on 100k nodes / 1.6M edges, HIDDEN=128.
// Round 4: gather128 -> one dst per 64-lane wave (parity-split halves, zero
// loop divergence, 8 source rows in flight, __shfl_xor(32) combine).
// Everything else unchanged from round 3 to isolate the delta.

#define HID 128

typedef __attribute__((ext_vector_type(4))) float f32x4;
typedef __attribute__((ext_vector_type(8))) short bf16x8;

__device__ __forceinline__ long long ld_idx(const void* p, long long i, int is64) {
    if (is64) return ((const long long*)p)[i];
    return (long long)((const int*)p)[i];
}

__device__ __forceinline__ unsigned short f2bf(float v) {
    unsigned u = __float_as_uint(v);
    unsigned r = (u + 0x7fffu + ((u >> 16) & 1u)) >> 16;
    return (unsigned short)r;
}
__device__ __forceinline__ float bf2f(unsigned short h) {
    return __uint_as_float(((unsigned)h) << 16);
}

// Probe whether edge_index arrived as int64 (high 32-bit words all zero) or int32.
__global__ void detect_kernel(const unsigned int* e, long long nwords, int* flag) {
    if (threadIdx.x == 0 && blockIdx.x == 0) {
        int is64 = 1;
        long long m = nwords < 256 ? nwords : 256;
        for (long long i = 1; i < m; i += 2)
            if (e[i] != 0u) { is64 = 0; break; }
        *flag = is64;
    }
}

// pass A: histogram + per-edge rank (single atomic pass)
__global__ void rank_kernel(const void* eidx, long long E, const int* flag,
                            int* __restrict__ cnt, int* __restrict__ rank) {
    long long i = (long long)blockIdx.x * blockDim.x + threadIdx.x;
    if (i >= E) return;
    int is64 = *flag;
    int d = (int)ld_idx(eidx, E + i, is64);
    rank[i] = atomicAdd(&cnt[d], 1);
}

__global__ void dinv_kernel(const int* cnt, float* dinv, int N) {
    int i = blockIdx.x * blockDim.x + threadIdx.x;
    if (i >= N) return;
    dinv[i] = rsqrtf((float)cnt[i] + 1.0f);   // +1 self-loop; always > 0
}

// exclusive scan of cnt[N] -> rowptr[N], 3-kernel
__global__ void scan1_kernel(const int* cnt, int* rowptr, int* bsum, int N) {
    __shared__ int s[256];
    int i = blockIdx.x * 256 + threadIdx.x;
    int v = (i < N) ? cnt[i] : 0;
    s[threadIdx.x] = v;
    __syncthreads();
    for (int off = 1; off < 256; off <<= 1) {
        int t = (threadIdx.x >= off) ? s[threadIdx.x - off] : 0;
        __syncthreads();
        s[threadIdx.x] += t;
        __syncthreads();
    }
    if (i < N) rowptr[i] = s[threadIdx.x] - v;   // exclusive
    if (threadIdx.x == 255) bsum[blockIdx.x] = s[255];
}

__global__ void scan2_kernel(int* bsum, int nb) {
    __shared__ int s[512];
    int t = threadIdx.x;
    int v = (t < nb) ? bsum[t] : 0;
    s[t] = v;
    __syncthreads();
    for (int off = 1; off < 512; off <<= 1) {
        int u = (t >= off) ? s[t - off] : 0;
        __syncthreads();
        s[t] += u;
        __syncthreads();
    }
    if (t < nb) bsum[t] = s[t] - v;   // exclusive block offsets
}

__global__ void scan3_kernel(int* rowptr, const int* bsum, int N, long long E) {
    int i = blockIdx.x * 256 + threadIdx.x;
    if (i < N) rowptr[i] += bsum[blockIdx.x];
    if (i == 0) rowptr[N] = (int)E;
}

// pass B: scatter src into CSR slot (no atomics)
__global__ void fill2_kernel(const void* eidx, long long E, const int* flag,
                             const int* __restrict__ rowptr, const int* __restrict__ rank,
                             int* __restrict__ csr) {
    long long i = (long long)blockIdx.x * blockDim.x + threadIdx.x;
    if (i >= E) return;
    int is64 = *flag;
    int s = (int)ld_idx(eidx, i, is64);
    int d = (int)ld_idx(eidx, E + i, is64);
    csr[rowptr[d] + rank[i]] = s;
}

// encoder aggregation (6-wide), thread per dst
__global__ void gather6_kernel(const int* __restrict__ rowptr, const int* __restrict__ csr,
                               const float* __restrict__ x, const float* __restrict__ dinv,
                               float* __restrict__ aggV, int N) {
    int i = blockIdx.x * blockDim.x + threadIdx.x;
    if (i >= N) return;
    int s = rowptr[i], e = rowptr[i + 1];
    float di = dinv[i];
    const float* xi = x + (long long)i * 6;
    float a0 = xi[0] * di, a1 = xi[1] * di, a2 = xi[2] * di;
    float a3 = xi[3] * di, a4 = xi[4] * di, a5 = xi[5] * di;
    for (int j = s; j < e; ++j) {
        int src = csr[j];
        float ds = dinv[src];
        const float* xs = x + (long long)src * 6;
        a0 += xs[0] * ds; a1 += xs[1] * ds; a2 += xs[2] * ds;
        a3 += xs[3] * ds; a4 += xs[4] * ds; a5 += xs[5] * ds;
    }
    float* o = aggV + (long long)i * 6;
    o[0] = a0 * di; o[1] = a1 * di; o[2] = a2 * di;
    o[3] = a3 * di; o[4] = a4 * di; o[5] = a5 * di;
}

// encoder matmul: h = relu(aggV @ W_enc + b), [N,6]@[6,128]
__global__ __launch_bounds__(256) void enc_kernel(const float* __restrict__ aggV,
                                                  const float* __restrict__ W,
                                                  const float* __restrict__ b,
                                                  float* __restrict__ h, int N) {
    __shared__ float Ws[6 * 128];
    __shared__ float bs[128];
    int t = threadIdx.x;
    if (t < 128) bs[t] = b[t];
    for (int i = t; i < 6 * 128; i += 256) Ws[i] = W[i];
    __syncthreads();
    long long node = (long long)blockIdx.x * 2 + (t >> 7);
    int c = t & 127;
    if (node >= N) return;
    float acc = bs[c];
#pragma unroll
    for (int k = 0; k < 6; ++k)
        acc = fmaf(aggV[node * 6 + k], Ws[k * 128 + c], acc);
    h[node * HID + c] = fmaxf(acc, 0.0f);
}

// W_hid -> fragment-ordered split-bf16: Wf[plane][nt][ks][lane][j]
// c = nt*16+(lane&15), k = ks*32+(lane>>4)*8+j, plane stride 16384
__global__ void wprep_kernel(const float* __restrict__ W, unsigned short* __restrict__ Wf) {
    int idx = blockIdx.x * 256 + threadIdx.x;
    if (idx >= 16384) return;
    int j = idx & 7;
    int lane = (idx >> 3) & 63;
    int ks = (idx >> 9) & 3;
    int nt = idx >> 11;
    int c = (nt << 4) + (lane & 15);
    int k = (ks << 5) + ((lane >> 4) << 3) + j;
    float v = W[k * 128 + c];
    unsigned short hi = f2bf(v);
    unsigned short lo = f2bf(v - bf2f(hi));
    Wf[idx] = hi;
    Wf[idx + 16384] = lo;
}

// hidden GEMM: G = (H @ W_hid) * dinv[row], split-bf16 MFMA (hi*hi+hi*lo+lo*hi).
__global__ __launch_bounds__(256) void gemm_mfma_kernel(const float* __restrict__ H,
                                                        const unsigned short* __restrict__ Wf,
                                                        const float* __restrict__ dinv,
                                                        float* __restrict__ G, int N) {
    __shared__ unsigned short Ahi[32 * 128];
    __shared__ unsigned short Alo[32 * 128];
    int tid = threadIdx.x;
    long long row0 = (long long)blockIdx.x * 32;
    const float4* H4 = (const float4*)(H + row0 * HID);
#pragma unroll
    for (int i = 0; i < 4; ++i) {
        int idx = tid + i * 256;              // float4 index, 1024 total
        int row = idx >> 5;                   // 0..31
        int k0 = (idx & 31) << 2;             // 0,4,...,124
        float4 v = make_float4(0.f, 0.f, 0.f, 0.f);
        if (row0 + row < N) v = H4[idx];
        unsigned short h0 = f2bf(v.x), h1 = f2bf(v.y), h2 = f2bf(v.z), h3 = f2bf(v.w);
        unsigned short l0 = f2bf(v.x - bf2f(h0));
        unsigned short l1 = f2bf(v.y - bf2f(h1));
        unsigned short l2 = f2bf(v.z - bf2f(h2));
        unsigned short l3 = f2bf(v.w - bf2f(h3));
        int sw = row * 128 + ((((k0 >> 3) ^ (row & 7)) << 3) | (k0 & 7));
        *(uint2*)&Ahi[sw] = make_uint2((unsigned)h0 | ((unsigned)h1 << 16),
                                       (unsigned)h2 | ((unsigned)h3 << 16));
        *(uint2*)&Alo[sw] = make_uint2((unsigned)l0 | ((unsigned)l1 << 16),
                                       (unsigned)l2 | ((unsigned)l3 << 16));
    }
    __syncthreads();
    int w = tid >> 6, lane = tid & 63;
    int msub = w & 1, nh = w >> 1;
    int arow = (msub << 4) + (lane & 15);
    int abase = arow * 128;
    f32x4 acc[4] = {};
    const bf16x8* Bf = (const bf16x8*)Wf;
#pragma unroll
    for (int ks = 0; ks < 4; ++ks) {
        int slot = (ks << 2) + (lane >> 4);
        int aoff = abase + ((slot ^ (arow & 7)) << 3);
        bf16x8 ah = *(const bf16x8*)&Ahi[aoff];
        bf16x8 al = *(const bf16x8*)&Alo[aoff];
#pragma unroll
        for (int t = 0; t < 4; ++t) {
            int g = ((((nh * 4 + t) << 2) + ks) << 6) + lane;
            bf16x8 bh = Bf[g];
            bf16x8 bl = Bf[g + 2048];
            acc[t] = __builtin_amdgcn_mfma_f32_16x16x32_bf16(ah, bh, acc[t], 0, 0, 0);
            acc[t] = __builtin_amdgcn_mfma_f32_16x16x32_bf16(ah, bl, acc[t], 0, 0, 0);
            acc[t] = __builtin_amdgcn_mfma_f32_16x16x32_bf16(al, bh, acc[t], 0, 0, 0);
        }
    }
    int rbase = (msub << 4) + ((lane >> 4) << 2);
    int cbase = (nh << 6) + (lane & 15);
#pragma unroll
    for (int t = 0; t < 4; ++t) {
        int col = cbase + (t << 4);
#pragma unroll
        for (int r = 0; r < 4; ++r) {
            long long grow = row0 + rbase + r;
            if (grow < N) G[grow * HID + col] = acc[t][r] * dinv[grow];
        }
    }
}

// hidden aggregation: ONE dst per 64-lane wave. Lane L owns column-quad (L&31)
// and parity slot (L>>5). Both halves walk identical trip counts (no loop
// divergence); each dwordx4 fetches 2 source rows; 8 rows in flight; halves
// combined with __shfl_xor(32) at the end.
__global__ __launch_bounds__(256) void gather128_kernel(const int* __restrict__ rowptr,
                                                        const int* __restrict__ csr,
                                                        const float* __restrict__ G,
                                                        const float* __restrict__ dinv,
                                                        const float* __restrict__ b,
                                                        float* __restrict__ H, int N) {
    int wv = (int)((blockIdx.x * 256u + threadIdx.x) >> 6);   // one dst per wave
    if (wv >= N) return;
    int lane = threadIdx.x & 63;
    int half = lane >> 5;
    int l32 = lane & 31;
    int s = rowptr[wv], e = rowptr[wv + 1];
    int deg = e - s;
    const float4* G4 = (const float4*)G;
    float4 acc = make_float4(0.f, 0.f, 0.f, 0.f);
    if (half == 0) acc = G4[(long long)wv * 32 + l32];   // self term (low half only)
    int nfull = deg >> 3;                                 // uniform across the wave
    const int* cp = csr + s + half;
    for (int it = 0; it < nfull; ++it) {
        int i0 = cp[it * 8 + 0];
        int i1 = cp[it * 8 + 2];
        int i2 = cp[it * 8 + 4];
        int i3 = cp[it * 8 + 6];
        float4 v0 = G4[(long long)i0 * 32 + l32];
        float4 v1 = G4[(long long)i1 * 32 + l32];
        float4 v2 = G4[(long long)i2 * 32 + l32];
        float4 v3 = G4[(long long)i3 * 32 + l32];
        acc.x += v0.x + v1.x + v2.x + v3.x;
        acc.y += v0.y + v1.y + v2.y + v3.y;
        acc.z += v0.z + v1.z + v2.z + v3.z;
        acc.w += v0.w + v1.w + v2.w + v3.w;
    }
    for (int j = s + nfull * 8 + half; j < e; j += 2) {   // <=4 iters, divergence <=1
        int i0 = csr[j];
        float4 v = G4[(long long)i0 * 32 + l32];
        acc.x += v.x; acc.y += v.y; acc.z += v.z; acc.w += v.w;
    }
    acc.x += __shfl_xor(acc.x, 32);
    acc.y += __shfl_xor(acc.y, 32);
    acc.z += __shfl_xor(acc.z, 32);
    acc.w += __shfl_xor(acc.w, 32);
    if (half == 0) {
        float di = dinv[wv];
        float4 bb = *(const float4*)&b[l32 * 4];
        float4 r;
        r.x = fmaxf(fmaf(acc.x, di, bb.x), 0.0f);
        r.y = fmaxf(fmaf(acc.y, di, bb.y), 0.0f);
        r.z = fmaxf(fmaf(acc.z, di, bb.z), 0.0f);
        r.w = fmaxf(fmaf(acc.w, di, bb.w), 0.0f);
        ((float4*)H)[(long long)wv * 32 + l32] = r;
    }
}

// decoder matmul: T3g = (h @ W_dec) * dinv[row], [N,128]@[128,3]
__global__ __launch_bounds__(256) void dec_kernel(const float* __restrict__ H,
                                                  const float* __restrict__ W,
                                                  const float* __restrict__ dinv,
                                                  float* __restrict__ T3g, int N) {
    __shared__ float Ws[128 * 3];
    int t = threadIdx.x;
    for (int i = t; i < 128 * 3; i += 256) Ws[i] = W[i];
    __syncthreads();
    long long node = (long long)blockIdx.x * 256 + t;
    if (node >= N) return;
    const float* h = H + node * HID;
    float a0 = 0.f, a1 = 0.f, a2 = 0.f;
    for (int k = 0; k < 128; k += 4) {
        float4 hv = *(const float4*)&h[k];
        a0 += hv.x * Ws[(k + 0) * 3] + hv.y * Ws[(k + 1) * 3] + hv.z * Ws[(k + 2) * 3] + hv.w * Ws[(k + 3) * 3];
        a1 += hv.x * Ws[(k + 0) * 3 + 1] + hv.y * Ws[(k + 1) * 3 + 1] + hv.z * Ws[(k + 2) * 3 + 1] + hv.w * Ws[(k + 3) * 3 + 1];
        a2 += hv.x * Ws[(k + 0) * 3 + 2] + hv.y * Ws[(k + 1) * 3 + 2] + hv.z * Ws[(k + 2) * 3 + 2] + hv.w * Ws[(k + 3) * 3 + 2];
    }
    float di = dinv[node];
    T3g[node * 3 + 0] = a0 * di;
    T3g[node * 3 + 1] = a1 * di;
    T3g[node * 3 + 2] = a2 * di;
}

// decoder aggregation (3-wide), thread per dst: out = dinv*(sum + self) + b
__global__ void gather3_kernel(const int* __restrict__ rowptr, const int* __restrict__ csr,
                               const float* __restrict__ T3g, const float* __restrict__ dinv,
                               const float* __restrict__ b, float* __restrict__ out, int N) {
    int i = blockIdx.x * blockDim.x + threadIdx.x;
    if (i >= N) return;
    int s = rowptr[i], e = rowptr[i + 1];
    const float* ti = T3g + (long long)i * 3;
    float a0 = ti[0], a1 = ti[1], a2 = ti[2];   // self
    for (int j = s; j < e; ++j) {
        int src = csr[j];
        const float* ts = T3g + (long long)src * 3;
        a0 += ts[0]; a1 += ts[1]; a2 += ts[2];
    }
    float di = dinv[i];
    float* o = out + (long long)i * 3;
    o[0] = fmaf(a0, di, b[0]);
    o[1] = fmaf(a1, di, b[1]);
    o[2] = fmaf(a2, di, b[2]);
}

extern "C" void kernel_launch(void* const* d_in, const int* in_sizes, int n_in,
                              void* d_out, int out_size, void* d_ws, size_t ws_size,
                              hipStream_t stream) {
    const float* x     = (const float*)d_in[0];
    const void* eidx   = d_in[1];
    const float* W_enc = (const float*)d_in[2];
    const float* b_enc = (const float*)d_in[3];
    const float* W_hid = (const float*)d_in[4];
    const float* b_hid = (const float*)d_in[5];
    const float* W_dec = (const float*)d_in[6];
    const float* b_dec = (const float*)d_in[7];

    const int N = in_sizes[0] / 6;          // 100000
    const long long E = in_sizes[1] / 2;    // 1600000
    const int NBLK = (N + 255) / 256;       // 391 (<= 512 for scan2)

    char* ws = (char*)d_ws;
    size_t off = 0;
    auto alloc = [&](size_t bytes) { char* p = ws + off; off += (bytes + 255) & ~(size_t)255; return p; };
    int*            flag   = (int*)alloc(4);
    float*          dinv   = (float*)alloc((size_t)N * 4);
    int*            cnt    = (int*)alloc((size_t)N * 4);
    int*            rowptr = (int*)alloc(((size_t)N + 1) * 4);
    int*            bsum   = (int*)alloc(2048 * 4);
    unsigned short* Wf     = (unsigned short*)alloc(2 * 16384 * 2);
    int*            csr    = (int*)alloc((size_t)E * 4);
    int*            rank   = (int*)alloc((size_t)E * 4);
    float*          aggV   = (float*)alloc((size_t)N * 6 * 4);   // encoder agg; reused as T3g
    float*          bufA   = (float*)alloc((size_t)N * HID * 4);
    float*          bufB   = (float*)alloc((size_t)N * HID * 4);

    detect_kernel<<<1, 64, 0, stream>>>((const unsigned int*)eidx, E * 2, flag);

    // CSR build: rank pass (histogram + ranks) -> dinv -> scan -> non-atomic fill
    hipMemsetAsync(cnt, 0, (size_t)N * 4, stream);
    rank_kernel<<<(int)((E + 255) / 256), 256, 0, stream>>>(eidx, E, flag, cnt, rank);
    dinv_kernel<<<NBLK, 256, 0, stream>>>(cnt, dinv, N);
    scan1_kernel<<<NBLK, 256, 0, stream>>>(cnt, rowptr, bsum, N);
    scan2_kernel<<<1, 512, 0, stream>>>(bsum, NBLK);
    scan3_kernel<<<NBLK, 256, 0, stream>>>(rowptr, bsum, N, E);
    fill2_kernel<<<(int)((E + 255) / 256), 256, 0, stream>>>(eidx, E, flag, rowptr, rank, csr);

    // W_hid fragment prep
    wprep_kernel<<<64, 256, 0, stream>>>(W_hid, Wf);

    // encoder
    gather6_kernel<<<NBLK, 256, 0, stream>>>(rowptr, csr, x, dinv, aggV, N);
    enc_kernel<<<(N + 1) / 2, 256, 0, stream>>>(aggV, W_enc, b_enc, bufA, N);

    // 4 hidden layers: MFMA GEMM + gather (one wave per dst: 4 dst/block)
    for (int l = 0; l < 4; ++l) {
        gemm_mfma_kernel<<<(N + 31) / 32, 256, 0, stream>>>(bufA, Wf, dinv, bufB, N);
        gather128_kernel<<<(N + 3) / 4, 256, 0, stream>>>(rowptr, csr, bufB, dinv, b_hid, bufA, N);
    }

    // decoder
    dec_kernel<<<(N + 255) / 256, 256, 0, stream>>>(bufA, W_dec, dinv, aggV, N);
    gather3_kernel<<<NBLK, 256, 0, stream>>>(rowptr, csr, aggV, dinv, b_dec, (float*)d_out, N);
}

// Round 5
// 612.709 us; speedup vs baseline: 19.3168x; 1.3456x over previous
//
#include <hip/hip_runtime.h>

// MeshGNN: 6-layer GCN on 100k nodes / 1.6M edges, HIDDEN=128.
// Round 5: message plane G stored in fp16 (GEMM epilogue rounds, gather
// accumulates fp32). Halves the gather's per-XCD compulsory L2-miss traffic
// (the measured invariant: FETCH ~400MB @ ~3.4TB/s across r2-r4 gathers).
// Everything else unchanged from round 4.

#define HID 128

typedef __attribute__((ext_vector_type(4))) float f32x4;
typedef __attribute__((ext_vector_type(8))) short bf16x8;
typedef __attribute__((ext_vector_type(4))) _Float16 half4;

__device__ __forceinline__ long long ld_idx(const void* p, long long i, int is64) {
    if (is64) return ((const long long*)p)[i];
    return (long long)((const int*)p)[i];
}

__device__ __forceinline__ unsigned short f2bf(float v) {
    unsigned u = __float_as_uint(v);
    unsigned r = (u + 0x7fffu + ((u >> 16) & 1u)) >> 16;
    return (unsigned short)r;
}
__device__ __forceinline__ float bf2f(unsigned short h) {
    return __uint_as_float(((unsigned)h) << 16);
}

// Probe whether edge_index arrived as int64 (high 32-bit words all zero) or int32.
__global__ void detect_kernel(const unsigned int* e, long long nwords, int* flag) {
    if (threadIdx.x == 0 && blockIdx.x == 0) {
        int is64 = 1;
        long long m = nwords < 256 ? nwords : 256;
        for (long long i = 1; i < m; i += 2)
            if (e[i] != 0u) { is64 = 0; break; }
        *flag = is64;
    }
}

// pass A: histogram + per-edge rank (single atomic pass)
__global__ void rank_kernel(const void* eidx, long long E, const int* flag,
                            int* __restrict__ cnt, int* __restrict__ rank) {
    long long i = (long long)blockIdx.x * blockDim.x + threadIdx.x;
    if (i >= E) return;
    int is64 = *flag;
    int d = (int)ld_idx(eidx, E + i, is64);
    rank[i] = atomicAdd(&cnt[d], 1);
}

__global__ void dinv_kernel(const int* cnt, float* dinv, int N) {
    int i = blockIdx.x * blockDim.x + threadIdx.x;
    if (i >= N) return;
    dinv[i] = rsqrtf((float)cnt[i] + 1.0f);   // +1 self-loop; always > 0
}

// exclusive scan of cnt[N] -> rowptr[N], 3-kernel
__global__ void scan1_kernel(const int* cnt, int* rowptr, int* bsum, int N) {
    __shared__ int s[256];
    int i = blockIdx.x * 256 + threadIdx.x;
    int v = (i < N) ? cnt[i] : 0;
    s[threadIdx.x] = v;
    __syncthreads();
    for (int off = 1; off < 256; off <<= 1) {
        int t = (threadIdx.x >= off) ? s[threadIdx.x - off] : 0;
        __syncthreads();
        s[threadIdx.x] += t;
        __syncthreads();
    }
    if (i < N) rowptr[i] = s[threadIdx.x] - v;   // exclusive
    if (threadIdx.x == 255) bsum[blockIdx.x] = s[255];
}

__global__ void scan2_kernel(int* bsum, int nb) {
    __shared__ int s[512];
    int t = threadIdx.x;
    int v = (t < nb) ? bsum[t] : 0;
    s[t] = v;
    __syncthreads();
    for (int off = 1; off < 512; off <<= 1) {
        int u = (t >= off) ? s[t - off] : 0;
        __syncthreads();
        s[t] += u;
        __syncthreads();
    }
    if (t < nb) bsum[t] = s[t] - v;   // exclusive block offsets
}

__global__ void scan3_kernel(int* rowptr, const int* bsum, int N, long long E) {
    int i = blockIdx.x * 256 + threadIdx.x;
    if (i < N) rowptr[i] += bsum[blockIdx.x];
    if (i == 0) rowptr[N] = (int)E;
}

// pass B: scatter src into CSR slot (no atomics)
__global__ void fill2_kernel(const void* eidx, long long E, const int* flag,
                             const int* __restrict__ rowptr, const int* __restrict__ rank,
                             int* __restrict__ csr) {
    long long i = (long long)blockIdx.x * blockDim.x + threadIdx.x;
    if (i >= E) return;
    int is64 = *flag;
    int s = (int)ld_idx(eidx, i, is64);
    int d = (int)ld_idx(eidx, E + i, is64);
    csr[rowptr[d] + rank[i]] = s;
}

// encoder aggregation (6-wide), thread per dst
__global__ void gather6_kernel(const int* __restrict__ rowptr, const int* __restrict__ csr,
                               const float* __restrict__ x, const float* __restrict__ dinv,
                               float* __restrict__ aggV, int N) {
    int i = blockIdx.x * blockDim.x + threadIdx.x;
    if (i >= N) return;
    int s = rowptr[i], e = rowptr[i + 1];
    float di = dinv[i];
    const float* xi = x + (long long)i * 6;
    float a0 = xi[0] * di, a1 = xi[1] * di, a2 = xi[2] * di;
    float a3 = xi[3] * di, a4 = xi[4] * di, a5 = xi[5] * di;
    for (int j = s; j < e; ++j) {
        int src = csr[j];
        float ds = dinv[src];
        const float* xs = x + (long long)src * 6;
        a0 += xs[0] * ds; a1 += xs[1] * ds; a2 += xs[2] * ds;
        a3 += xs[3] * ds; a4 += xs[4] * ds; a5 += xs[5] * ds;
    }
    float* o = aggV + (long long)i * 6;
    o[0] = a0 * di; o[1] = a1 * di; o[2] = a2 * di;
    o[3] = a3 * di; o[4] = a4 * di; o[5] = a5 * di;
}

// encoder matmul: h = relu(aggV @ W_enc + b), [N,6]@[6,128]
__global__ __launch_bounds__(256) void enc_kernel(const float* __restrict__ aggV,
                                                  const float* __restrict__ W,
                                                  const float* __restrict__ b,
                                                  float* __restrict__ h, int N) {
    __shared__ float Ws[6 * 128];
    __shared__ float bs[128];
    int t = threadIdx.x;
    if (t < 128) bs[t] = b[t];
    for (int i = t; i < 6 * 128; i += 256) Ws[i] = W[i];
    __syncthreads();
    long long node = (long long)blockIdx.x * 2 + (t >> 7);
    int c = t & 127;
    if (node >= N) return;
    float acc = bs[c];
#pragma unroll
    for (int k = 0; k < 6; ++k)
        acc = fmaf(aggV[node * 6 + k], Ws[k * 128 + c], acc);
    h[node * HID + c] = fmaxf(acc, 0.0f);
}

// W_hid -> fragment-ordered split-bf16: Wf[plane][nt][ks][lane][j]
// c = nt*16+(lane&15), k = ks*32+(lane>>4)*8+j, plane stride 16384
__global__ void wprep_kernel(const float* __restrict__ W, unsigned short* __restrict__ Wf) {
    int idx = blockIdx.x * 256 + threadIdx.x;
    if (idx >= 16384) return;
    int j = idx & 7;
    int lane = (idx >> 3) & 63;
    int ks = (idx >> 9) & 3;
    int nt = idx >> 11;
    int c = (nt << 4) + (lane & 15);
    int k = (ks << 5) + ((lane >> 4) << 3) + j;
    float v = W[k * 128 + c];
    unsigned short hi = f2bf(v);
    unsigned short lo = f2bf(v - bf2f(hi));
    Wf[idx] = hi;
    Wf[idx + 16384] = lo;
}

// hidden GEMM: Gh = fp16((H @ W_hid) * dinv[row]), split-bf16 MFMA.
__global__ __launch_bounds__(256) void gemm_mfma_kernel(const float* __restrict__ H,
                                                        const unsigned short* __restrict__ Wf,
                                                        const float* __restrict__ dinv,
                                                        _Float16* __restrict__ Gh, int N) {
    __shared__ unsigned short Ahi[32 * 128];
    __shared__ unsigned short Alo[32 * 128];
    int tid = threadIdx.x;
    long long row0 = (long long)blockIdx.x * 32;
    const float4* H4 = (const float4*)(H + row0 * HID);
#pragma unroll
    for (int i = 0; i < 4; ++i) {
        int idx = tid + i * 256;              // float4 index, 1024 total
        int row = idx >> 5;                   // 0..31
        int k0 = (idx & 31) << 2;             // 0,4,...,124
        float4 v = make_float4(0.f, 0.f, 0.f, 0.f);
        if (row0 + row < N) v = H4[idx];
        unsigned short h0 = f2bf(v.x), h1 = f2bf(v.y), h2 = f2bf(v.z), h3 = f2bf(v.w);
        unsigned short l0 = f2bf(v.x - bf2f(h0));
        unsigned short l1 = f2bf(v.y - bf2f(h1));
        unsigned short l2 = f2bf(v.z - bf2f(h2));
        unsigned short l3 = f2bf(v.w - bf2f(h3));
        int sw = row * 128 + ((((k0 >> 3) ^ (row & 7)) << 3) | (k0 & 7));
        *(uint2*)&Ahi[sw] = make_uint2((unsigned)h0 | ((unsigned)h1 << 16),
                                       (unsigned)h2 | ((unsigned)h3 << 16));
        *(uint2*)&Alo[sw] = make_uint2((unsigned)l0 | ((unsigned)l1 << 16),
                                       (unsigned)l2 | ((unsigned)l3 << 16));
    }
    __syncthreads();
    int w = tid >> 6, lane = tid & 63;
    int msub = w & 1, nh = w >> 1;
    int arow = (msub << 4) + (lane & 15);
    int abase = arow * 128;
    f32x4 acc[4] = {};
    const bf16x8* Bf = (const bf16x8*)Wf;
#pragma unroll
    for (int ks = 0; ks < 4; ++ks) {
        int slot = (ks << 2) + (lane >> 4);
        int aoff = abase + ((slot ^ (arow & 7)) << 3);
        bf16x8 ah = *(const bf16x8*)&Ahi[aoff];
        bf16x8 al = *(const bf16x8*)&Alo[aoff];
#pragma unroll
        for (int t = 0; t < 4; ++t) {
            int g = ((((nh * 4 + t) << 2) + ks) << 6) + lane;
            bf16x8 bh = Bf[g];
            bf16x8 bl = Bf[g + 2048];
            acc[t] = __builtin_amdgcn_mfma_f32_16x16x32_bf16(ah, bh, acc[t], 0, 0, 0);
            acc[t] = __builtin_amdgcn_mfma_f32_16x16x32_bf16(ah, bl, acc[t], 0, 0, 0);
            acc[t] = __builtin_amdgcn_mfma_f32_16x16x32_bf16(al, bh, acc[t], 0, 0, 0);
        }
    }
    int rbase = (msub << 4) + ((lane >> 4) << 2);
    int cbase = (nh << 6) + (lane & 15);
#pragma unroll
    for (int t = 0; t < 4; ++t) {
        int col = cbase + (t << 4);
#pragma unroll
        for (int r = 0; r < 4; ++r) {
            long long grow = row0 + rbase + r;
            if (grow < N) Gh[grow * HID + col] = (_Float16)(acc[t][r] * dinv[grow]);
        }
    }
}

// hidden aggregation: ONE dst per 64-lane wave, fp16 messages, fp32 accum.
// Lane L owns column-quad (L&31) and parity slot (L>>5); 8B (4 halves) per
// lane per row; halves combined with __shfl_xor(32).
__global__ __launch_bounds__(256) void gather128_kernel(const int* __restrict__ rowptr,
                                                        const int* __restrict__ csr,
                                                        const _Float16* __restrict__ Gh,
                                                        const float* __restrict__ dinv,
                                                        const float* __restrict__ b,
                                                        float* __restrict__ H, int N) {
    int wv = (int)((blockIdx.x * 256u + threadIdx.x) >> 6);   // one dst per wave
    if (wv >= N) return;
    int lane = threadIdx.x & 63;
    int half = lane >> 5;
    int l32 = lane & 31;
    int s = rowptr[wv], e = rowptr[wv + 1];
    int deg = e - s;
    const half4* G4 = (const half4*)Gh;   // row = 32 half4s
    float4 acc = make_float4(0.f, 0.f, 0.f, 0.f);
    if (half == 0) {
        half4 sv = G4[(long long)wv * 32 + l32];   // self term (low half only)
        acc.x = (float)sv.x; acc.y = (float)sv.y;
        acc.z = (float)sv.z; acc.w = (float)sv.w;
    }
    int nfull = deg >> 3;                                 // uniform across the wave
    const int* cp = csr + s + half;
    for (int it = 0; it < nfull; ++it) {
        int i0 = cp[it * 8 + 0];
        int i1 = cp[it * 8 + 2];
        int i2 = cp[it * 8 + 4];
        int i3 = cp[it * 8 + 6];
        half4 v0 = G4[(long long)i0 * 32 + l32];
        half4 v1 = G4[(long long)i1 * 32 + l32];
        half4 v2 = G4[(long long)i2 * 32 + l32];
        half4 v3 = G4[(long long)i3 * 32 + l32];
        acc.x += (float)v0.x + (float)v1.x + (float)v2.x + (float)v3.x;
        acc.y += (float)v0.y + (float)v1.y + (float)v2.y + (float)v3.y;
        acc.z += (float)v0.z + (float)v1.z + (float)v2.z + (float)v3.z;
        acc.w += (float)v0.w + (float)v1.w + (float)v2.w + (float)v3.w;
    }
    for (int j = s + nfull * 8 + half; j < e; j += 2) {   // tail, divergence <=1
        int i0 = csr[j];
        half4 v = G4[(long long)i0 * 32 + l32];
        acc.x += (float)v.x; acc.y += (float)v.y;
        acc.z += (float)v.z; acc.w += (float)v.w;
    }
    acc.x += __shfl_xor(acc.x, 32);
    acc.y += __shfl_xor(acc.y, 32);
    acc.z += __shfl_xor(acc.z, 32);
    acc.w += __shfl_xor(acc.w, 32);
    if (half == 0) {
        float di = dinv[wv];
        float4 bb = *(const float4*)&b[l32 * 4];
        float4 r;
        r.x = fmaxf(fmaf(acc.x, di, bb.x), 0.0f);
        r.y = fmaxf(fmaf(acc.y, di, bb.y), 0.0f);
        r.z = fmaxf(fmaf(acc.z, di, bb.z), 0.0f);
        r.w = fmaxf(fmaf(acc.w, di, bb.w), 0.0f);
        ((float4*)H)[(long long)wv * 32 + l32] = r;
    }
}

// decoder matmul: T3g = (h @ W_dec) * dinv[row], [N,128]@[128,3]
__global__ __launch_bounds__(256) void dec_kernel(const float* __restrict__ H,
                                                  const float* __restrict__ W,
                                                  const float* __restrict__ dinv,
                                                  float* __restrict__ T3g, int N) {
    __shared__ float Ws[128 * 3];
    int t = threadIdx.x;
    for (int i = t; i < 128 * 3; i += 256) Ws[i] = W[i];
    __syncthreads();
    long long node = (long long)blockIdx.x * 256 + t;
    if (node >= N) return;
    const float* h = H + node * HID;
    float a0 = 0.f, a1 = 0.f, a2 = 0.f;
    for (int k = 0; k < 128; k += 4) {
        float4 hv = *(const float4*)&h[k];
        a0 += hv.x * Ws[(k + 0) * 3] + hv.y * Ws[(k + 1) * 3] + hv.z * Ws[(k + 2) * 3] + hv.w * Ws[(k + 3) * 3];
        a1 += hv.x * Ws[(k + 0) * 3 + 1] + hv.y * Ws[(k + 1) * 3 + 1] + hv.z * Ws[(k + 2) * 3 + 1] + hv.w * Ws[(k + 3) * 3 + 1];
        a2 += hv.x * Ws[(k + 0) * 3 + 2] + hv.y * Ws[(k + 1) * 3 + 2] + hv.z * Ws[(k + 2) * 3 + 2] + hv.w * Ws[(k + 3) * 3 + 2];
    }
    float di = dinv[node];
    T3g[node * 3 + 0] = a0 * di;
    T3g[node * 3 + 1] = a1 * di;
    T3g[node * 3 + 2] = a2 * di;
}

// decoder aggregation (3-wide), thread per dst: out = dinv*(sum + self) + b
__global__ void gather3_kernel(const int* __restrict__ rowptr, const int* __restrict__ csr,
                               const float* __restrict__ T3g, const float* __restrict__ dinv,
                               const float* __restrict__ b, float* __restrict__ out, int N) {
    int i = blockIdx.x * blockDim.x + threadIdx.x;
    if (i >= N) return;
    int s = rowptr[i], e = rowptr[i + 1];
    const float* ti = T3g + (long long)i * 3;
    float a0 = ti[0], a1 = ti[1], a2 = ti[2];   // self
    for (int j = s; j < e; ++j) {
        int src = csr[j];
        const float* ts = T3g + (long long)src * 3;
        a0 += ts[0]; a1 += ts[1]; a2 += ts[2];
    }
    float di = dinv[i];
    float* o = out + (long long)i * 3;
    o[0] = fmaf(a0, di, b[0]);
    o[1] = fmaf(a1, di, b[1]);
    o[2] = fmaf(a2, di, b[2]);
}

extern "C" void kernel_launch(void* const* d_in, const int* in_sizes, int n_in,
                              void* d_out, int out_size, void* d_ws, size_t ws_size,
                              hipStream_t stream) {
    const float* x     = (const float*)d_in[0];
    const void* eidx   = d_in[1];
    const float* W_enc = (const float*)d_in[2];
    const float* b_enc = (const float*)d_in[3];
    const float* W_hid = (const float*)d_in[4];
    const float* b_hid = (const float*)d_in[5];
    const float* W_dec = (const float*)d_in[6];
    const float* b_dec = (const float*)d_in[7];

    const int N = in_sizes[0] / 6;          // 100000
    const long long E = in_sizes[1] / 2;    // 1600000
    const int NBLK = (N + 255) / 256;       // 391 (<= 512 for scan2)

    char* ws = (char*)d_ws;
    size_t off = 0;
    auto alloc = [&](size_t bytes) { char* p = ws + off; off += (bytes + 255) & ~(size_t)255; return p; };
    int*            flag   = (int*)alloc(4);
    float*          dinv   = (float*)alloc((size_t)N * 4);
    int*            cnt    = (int*)alloc((size_t)N * 4);
    int*            rowptr = (int*)alloc(((size_t)N + 1) * 4);
    int*            bsum   = (int*)alloc(2048 * 4);
    unsigned short* Wf     = (unsigned short*)alloc(2 * 16384 * 2);
    int*            csr    = (int*)alloc((size_t)E * 4);
    int*            rank   = (int*)alloc((size_t)E * 4);
    float*          aggV   = (float*)alloc((size_t)N * 6 * 4);   // encoder agg; reused as T3g
    float*          bufA   = (float*)alloc((size_t)N * HID * 4); // fp32 activations
    _Float16*       bufG   = (_Float16*)alloc((size_t)N * HID * 2); // fp16 messages

    detect_kernel<<<1, 64, 0, stream>>>((const unsigned int*)eidx, E * 2, flag);

    // CSR build: rank pass (histogram + ranks) -> dinv -> scan -> non-atomic fill
    hipMemsetAsync(cnt, 0, (size_t)N * 4, stream);
    rank_kernel<<<(int)((E + 255) / 256), 256, 0, stream>>>(eidx, E, flag, cnt, rank);
    dinv_kernel<<<NBLK, 256, 0, stream>>>(cnt, dinv, N);
    scan1_kernel<<<NBLK, 256, 0, stream>>>(cnt, rowptr, bsum, N);
    scan2_kernel<<<1, 512, 0, stream>>>(bsum, NBLK);
    scan3_kernel<<<NBLK, 256, 0, stream>>>(rowptr, bsum, N, E);
    fill2_kernel<<<(int)((E + 255) / 256), 256, 0, stream>>>(eidx, E, flag, rowptr, rank, csr);

    // W_hid fragment prep
    wprep_kernel<<<64, 256, 0, stream>>>(W_hid, Wf);

    // encoder
    gather6_kernel<<<NBLK, 256, 0, stream>>>(rowptr, csr, x, dinv, aggV, N);
    enc_kernel<<<(N + 1) / 2, 256, 0, stream>>>(aggV, W_enc, b_enc, bufA, N);

    // 4 hidden layers: MFMA GEMM (fp16 out) + gather (one wave per dst)
    for (int l = 0; l < 4; ++l) {
        gemm_mfma_kernel<<<(N + 31) / 32, 256, 0, stream>>>(bufA, Wf, dinv, bufG, N);
        gather128_kernel<<<(N + 3) / 4, 256, 0, stream>>>(rowptr, csr, bufG, dinv, b_hid, bufA, N);
    }

    // decoder
    dec_kernel<<<(N + 255) / 256, 256, 0, stream>>>(bufA, W_dec, dinv, aggV, N);
    gather3_kernel<<<NBLK, 256, 0, stream>>>(rowptr, csr, aggV, dinv, b_dec, (float*)d_out, N);
}

// Round 6
// 503.650 us; speedup vs baseline: 23.4997x; 1.2165x over previous
//
#include <hip/hip_runtime.h>

// MeshGNN: 6-layer GCN on 100k nodes / 1.6M edges, HIDDEN=128.
// Round 6: fuse around the fp16 G-plane. fp32 activations never hit global:
//   encF  = enc-matmul + gemm1            -> G1
//   fused = gather(G_l) + relu + gemm     -> G_{l+1}   (x3)
//   g4dec = gather(G4) + relu + dec-matmul -> T3g      (16-row unrolled gather
//           as the isolated concurrency probe: 8 loads in flight vs 4)
// CSR build (rank trick), gather6, gather3 unchanged from round 5.

#define HID 128

typedef __attribute__((ext_vector_type(4))) float f32x4;
typedef __attribute__((ext_vector_type(8))) short bf16x8;
typedef __attribute__((ext_vector_type(4))) _Float16 half4;

__device__ __forceinline__ long long ld_idx(const void* p, long long i, int is64) {
    if (is64) return ((const long long*)p)[i];
    return (long long)((const int*)p)[i];
}

__device__ __forceinline__ unsigned short f2bf(float v) {
    unsigned u = __float_as_uint(v);
    unsigned r = (u + 0x7fffu + ((u >> 16) & 1u)) >> 16;
    return (unsigned short)r;
}
__device__ __forceinline__ float bf2f(unsigned short h) {
    return __uint_as_float(((unsigned)h) << 16);
}

// Probe whether edge_index arrived as int64 (high 32-bit words all zero) or int32.
__global__ void detect_kernel(const unsigned int* e, long long nwords, int* flag) {
    if (threadIdx.x == 0 && blockIdx.x == 0) {
        int is64 = 1;
        long long m = nwords < 256 ? nwords : 256;
        for (long long i = 1; i < m; i += 2)
            if (e[i] != 0u) { is64 = 0; break; }
        *flag = is64;
    }
}

__global__ void rank_kernel(const void* eidx, long long E, const int* flag,
                            int* __restrict__ cnt, int* __restrict__ rank) {
    long long i = (long long)blockIdx.x * blockDim.x + threadIdx.x;
    if (i >= E) return;
    int is64 = *flag;
    int d = (int)ld_idx(eidx, E + i, is64);
    rank[i] = atomicAdd(&cnt[d], 1);
}

__global__ void dinv_kernel(const int* cnt, float* dinv, int N) {
    int i = blockIdx.x * blockDim.x + threadIdx.x;
    if (i >= N) return;
    dinv[i] = rsqrtf((float)cnt[i] + 1.0f);   // +1 self-loop; always > 0
}

__global__ void scan1_kernel(const int* cnt, int* rowptr, int* bsum, int N) {
    __shared__ int s[256];
    int i = blockIdx.x * 256 + threadIdx.x;
    int v = (i < N) ? cnt[i] : 0;
    s[threadIdx.x] = v;
    __syncthreads();
    for (int off = 1; off < 256; off <<= 1) {
        int t = (threadIdx.x >= off) ? s[threadIdx.x - off] : 0;
        __syncthreads();
        s[threadIdx.x] += t;
        __syncthreads();
    }
    if (i < N) rowptr[i] = s[threadIdx.x] - v;   // exclusive
    if (threadIdx.x == 255) bsum[blockIdx.x] = s[255];
}

__global__ void scan2_kernel(int* bsum, int nb) {
    __shared__ int s[512];
    int t = threadIdx.x;
    int v = (t < nb) ? bsum[t] : 0;
    s[t] = v;
    __syncthreads();
    for (int off = 1; off < 512; off <<= 1) {
        int u = (t >= off) ? s[t - off] : 0;
        __syncthreads();
        s[t] += u;
        __syncthreads();
    }
    if (t < nb) bsum[t] = s[t] - v;
}

__global__ void scan3_kernel(int* rowptr, const int* bsum, int N, long long E) {
    int i = blockIdx.x * 256 + threadIdx.x;
    if (i < N) rowptr[i] += bsum[blockIdx.x];
    if (i == 0) rowptr[N] = (int)E;
}

__global__ void fill2_kernel(const void* eidx, long long E, const int* flag,
                             const int* __restrict__ rowptr, const int* __restrict__ rank,
                             int* __restrict__ csr) {
    long long i = (long long)blockIdx.x * blockDim.x + threadIdx.x;
    if (i >= E) return;
    int is64 = *flag;
    int s = (int)ld_idx(eidx, i, is64);
    int d = (int)ld_idx(eidx, E + i, is64);
    csr[rowptr[d] + rank[i]] = s;
}

// encoder aggregation (6-wide), thread per dst
__global__ void gather6_kernel(const int* __restrict__ rowptr, const int* __restrict__ csr,
                               const float* __restrict__ x, const float* __restrict__ dinv,
                               float* __restrict__ aggV, int N) {
    int i = blockIdx.x * blockDim.x + threadIdx.x;
    if (i >= N) return;
    int s = rowptr[i], e = rowptr[i + 1];
    float di = dinv[i];
    const float* xi = x + (long long)i * 6;
    float a0 = xi[0] * di, a1 = xi[1] * di, a2 = xi[2] * di;
    float a3 = xi[3] * di, a4 = xi[4] * di, a5 = xi[5] * di;
    for (int j = s; j < e; ++j) {
        int src = csr[j];
        float ds = dinv[src];
        const float* xs = x + (long long)src * 6;
        a0 += xs[0] * ds; a1 += xs[1] * ds; a2 += xs[2] * ds;
        a3 += xs[3] * ds; a4 += xs[4] * ds; a5 += xs[5] * ds;
    }
    float* o = aggV + (long long)i * 6;
    o[0] = a0 * di; o[1] = a1 * di; o[2] = a2 * di;
    o[3] = a3 * di; o[4] = a4 * di; o[5] = a5 * di;
}

// W_hid -> fragment-ordered split-bf16 (unchanged layout from r3-r5)
__global__ void wprep_kernel(const float* __restrict__ W, unsigned short* __restrict__ Wf) {
    int idx = blockIdx.x * 256 + threadIdx.x;
    if (idx >= 16384) return;
    int j = idx & 7;
    int lane = (idx >> 3) & 63;
    int ks = (idx >> 9) & 3;
    int nt = idx >> 11;
    int c = (nt << 4) + (lane & 15);
    int k = (ks << 5) + ((lane >> 4) << 3) + j;
    float v = W[k * 128 + c];
    unsigned short hi = f2bf(v);
    unsigned short lo = f2bf(v - bf2f(hi));
    Wf[idx] = hi;
    Wf[idx + 16384] = lo;
}

// ---- shared device pieces ----

// 8-row-unrolled gather of one dst row (pre-shfl partial; parity-split halves)
__device__ __forceinline__ float4 gather_row8(const int* __restrict__ rowptr,
                                              const int* __restrict__ csr,
                                              const half4* __restrict__ G4,
                                              int wv, int l32, int half) {
    int s = rowptr[wv], e = rowptr[wv + 1];
    int deg = e - s;
    float4 acc = make_float4(0.f, 0.f, 0.f, 0.f);
    if (half == 0) {
        half4 sv = G4[(long long)wv * 32 + l32];
        acc.x = (float)sv.x; acc.y = (float)sv.y; acc.z = (float)sv.z; acc.w = (float)sv.w;
    }
    int nfull = deg >> 3;
    const int* cp = csr + s + half;
    for (int it = 0; it < nfull; ++it) {
        int i0 = cp[0], i1 = cp[2], i2 = cp[4], i3 = cp[6];
        half4 v0 = G4[(long long)i0 * 32 + l32];
        half4 v1 = G4[(long long)i1 * 32 + l32];
        half4 v2 = G4[(long long)i2 * 32 + l32];
        half4 v3 = G4[(long long)i3 * 32 + l32];
        acc.x += (float)v0.x + (float)v1.x + (float)v2.x + (float)v3.x;
        acc.y += (float)v0.y + (float)v1.y + (float)v2.y + (float)v3.y;
        acc.z += (float)v0.z + (float)v1.z + (float)v2.z + (float)v3.z;
        acc.w += (float)v0.w + (float)v1.w + (float)v2.w + (float)v3.w;
        cp += 8;
    }
    for (int j = s + nfull * 8 + half; j < e; j += 2) {
        int i0 = csr[j];
        half4 v = G4[(long long)i0 * 32 + l32];
        acc.x += (float)v.x; acc.y += (float)v.y; acc.z += (float)v.z; acc.w += (float)v.w;
    }
    return acc;
}

// 16-row-unrolled variant: 8 independent loads in flight (concurrency probe)
__device__ __forceinline__ float4 gather_row16(const int* __restrict__ rowptr,
                                               const int* __restrict__ csr,
                                               const half4* __restrict__ G4,
                                               int wv, int l32, int half) {
    int s = rowptr[wv], e = rowptr[wv + 1];
    int deg = e - s;
    float4 acc = make_float4(0.f, 0.f, 0.f, 0.f);
    if (half == 0) {
        half4 sv = G4[(long long)wv * 32 + l32];
        acc.x = (float)sv.x; acc.y = (float)sv.y; acc.z = (float)sv.z; acc.w = (float)sv.w;
    }
    const int* cp = csr + s + half;
    int n16 = deg >> 4;
    for (int it = 0; it < n16; ++it) {
        int i0 = cp[0], i1 = cp[2], i2 = cp[4], i3 = cp[6];
        int i4 = cp[8], i5 = cp[10], i6 = cp[12], i7 = cp[14];
        half4 v0 = G4[(long long)i0 * 32 + l32];
        half4 v1 = G4[(long long)i1 * 32 + l32];
        half4 v2 = G4[(long long)i2 * 32 + l32];
        half4 v3 = G4[(long long)i3 * 32 + l32];
        half4 v4 = G4[(long long)i4 * 32 + l32];
        half4 v5 = G4[(long long)i5 * 32 + l32];
        half4 v6 = G4[(long long)i6 * 32 + l32];
        half4 v7 = G4[(long long)i7 * 32 + l32];
        acc.x += ((float)v0.x + (float)v1.x) + ((float)v2.x + (float)v3.x)
               + ((float)v4.x + (float)v5.x) + ((float)v6.x + (float)v7.x);
        acc.y += ((float)v0.y + (float)v1.y) + ((float)v2.y + (float)v3.y)
               + ((float)v4.y + (float)v5.y) + ((float)v6.y + (float)v7.y);
        acc.z += ((float)v0.z + (float)v1.z) + ((float)v2.z + (float)v3.z)
               + ((float)v4.z + (float)v5.z) + ((float)v6.z + (float)v7.z);
        acc.w += ((float)v0.w + (float)v1.w) + ((float)v2.w + (float)v3.w)
               + ((float)v4.w + (float)v5.w) + ((float)v6.w + (float)v7.w);
        cp += 16;
    }
    if (deg & 8) {
        int i0 = cp[0], i1 = cp[2], i2 = cp[4], i3 = cp[6];
        half4 v0 = G4[(long long)i0 * 32 + l32];
        half4 v1 = G4[(long long)i1 * 32 + l32];
        half4 v2 = G4[(long long)i2 * 32 + l32];
        half4 v3 = G4[(long long)i3 * 32 + l32];
        acc.x += (float)v0.x + (float)v1.x + (float)v2.x + (float)v3.x;
        acc.y += (float)v0.y + (float)v1.y + (float)v2.y + (float)v3.y;
        acc.z += (float)v0.z + (float)v1.z + (float)v2.z + (float)v3.z;
        acc.w += (float)v0.w + (float)v1.w + (float)v2.w + (float)v3.w;
    }
    for (int j = s + (deg & ~7) + half; j < e; j += 2) {
        int i0 = csr[j];
        half4 v = G4[(long long)i0 * 32 + l32];
        acc.x += (float)v.x; acc.y += (float)v.y; acc.z += (float)v.z; acc.w += (float)v.w;
    }
    return acc;
}

// MFMA phase: 16 rows (LDS split-bf16) x W_hid-fragments -> Gout fp16, x dinv[row]
__device__ __forceinline__ void mfma_phase(const unsigned short* Ahi, const unsigned short* Alo,
                                           const unsigned short* __restrict__ Wf,
                                           const float* dinvS, _Float16* __restrict__ Gout,
                                           long long base, int N, int w, int lane) {
    int arow = lane & 15;
    int abase = arow * 128;
    f32x4 acc = {};
    const bf16x8* Bf = (const bf16x8*)Wf;
#pragma unroll
    for (int ks = 0; ks < 4; ++ks) {
        int slot = (ks << 2) + (lane >> 4);
        int aoff = abase + ((slot ^ (arow & 7)) << 3);
        bf16x8 ah = *(const bf16x8*)&Ahi[aoff];
        bf16x8 al = *(const bf16x8*)&Alo[aoff];
        int g = (((w << 2) + ks) << 6) + lane;
        bf16x8 bh = Bf[g];
        bf16x8 bl = Bf[g + 2048];
        acc = __builtin_amdgcn_mfma_f32_16x16x32_bf16(ah, bh, acc, 0, 0, 0);
        acc = __builtin_amdgcn_mfma_f32_16x16x32_bf16(ah, bl, acc, 0, 0, 0);
        acc = __builtin_amdgcn_mfma_f32_16x16x32_bf16(al, bh, acc, 0, 0, 0);
    }
    int rbase = (lane >> 4) << 2;
    int col = (w << 4) + (lane & 15);
#pragma unroll
    for (int r = 0; r < 4; ++r) {
        int lrow = rbase + r;
        long long grow = base + lrow;
        if (grow < N) Gout[grow * HID + col] = (_Float16)(acc[r] * dinvS[lrow]);
    }
}

// split h (fp32 float4, cols 4*l32..+4) into bf16 hi/lo planes in swizzled LDS
__device__ __forceinline__ void split_write(unsigned short* Ahi, unsigned short* Alo,
                                            float4 h, int lrow, int l32, int half) {
    unsigned short h0 = f2bf(h.x), h1 = f2bf(h.y), h2 = f2bf(h.z), h3 = f2bf(h.w);
    int slot = l32 >> 1;
    int off = lrow * 128 + (((slot ^ (lrow & 7)) << 3) | ((l32 & 1) << 2));
    if (half == 0) {
        *(uint2*)&Ahi[off] = make_uint2((unsigned)h0 | ((unsigned)h1 << 16),
                                        (unsigned)h2 | ((unsigned)h3 << 16));
    } else {
        unsigned short l0 = f2bf(h.x - bf2f(h0));
        unsigned short l1 = f2bf(h.y - bf2f(h1));
        unsigned short l2 = f2bf(h.z - bf2f(h2));
        unsigned short l3 = f2bf(h.w - bf2f(h3));
        *(uint2*)&Alo[off] = make_uint2((unsigned)l0 | ((unsigned)l1 << 16),
                                        (unsigned)l2 | ((unsigned)l3 << 16));
    }
}

// encF: h0 = relu(aggV @ W_enc + b_enc); G1 = (h0 @ W_hid) * dinv  (16 nodes/block)
__global__ __launch_bounds__(512) void encF_kernel(const float* __restrict__ aggV,
                                                   const float* __restrict__ Wenc,
                                                   const float* __restrict__ benc,
                                                   const unsigned short* __restrict__ Wf,
                                                   const float* __restrict__ dinv,
                                                   _Float16* __restrict__ Gout, int N) {
    __shared__ unsigned short Ahi[16 * 128];
    __shared__ unsigned short Alo[16 * 128];
    __shared__ float WencS[6 * 128];
    __shared__ float dinvS[16];
    int tid = threadIdx.x;
    for (int i = tid; i < 768; i += 512) WencS[i] = Wenc[i];
    __syncthreads();
    int w = tid >> 6, lane = tid & 63, half = lane >> 5, l32 = lane & 31;
    long long base = (long long)blockIdx.x * 16;
#pragma unroll
    for (int rr = 0; rr < 2; ++rr) {
        int lrow = w + rr * 8;
        long long node = base + lrow;
        float4 h = make_float4(0.f, 0.f, 0.f, 0.f);
        float di = 0.f;
        if (node < N) {
            di = dinv[node];
            const float* av = aggV + node * 6;
            float a0 = av[0], a1 = av[1], a2 = av[2], a3 = av[3], a4 = av[4], a5 = av[5];
            float4 bb = *(const float4*)&benc[l32 * 4];
            int c = l32 * 4;
            h = bb;
#define EK(AK, K)                                                   \
            h.x = fmaf(AK, WencS[(K) * 128 + c + 0], h.x);          \
            h.y = fmaf(AK, WencS[(K) * 128 + c + 1], h.y);          \
            h.z = fmaf(AK, WencS[(K) * 128 + c + 2], h.z);          \
            h.w = fmaf(AK, WencS[(K) * 128 + c + 3], h.w);
            EK(a0, 0) EK(a1, 1) EK(a2, 2) EK(a3, 3) EK(a4, 4) EK(a5, 5)
#undef EK
            h.x = fmaxf(h.x, 0.f); h.y = fmaxf(h.y, 0.f);
            h.z = fmaxf(h.z, 0.f); h.w = fmaxf(h.w, 0.f);
        }
        if (lane == 0) dinvS[lrow] = di;
        split_write(Ahi, Alo, h, lrow, l32, half);
    }
    __syncthreads();
    mfma_phase(Ahi, Alo, Wf, dinvS, Gout, base, N, w, lane);
}

// fused hidden step: h = relu(dinv*(gather G) + b); Gout = (h @ W_hid) * dinv
__global__ __launch_bounds__(512) void fused_kernel(const int* __restrict__ rowptr,
                                                    const int* __restrict__ csr,
                                                    const _Float16* __restrict__ Gin,
                                                    const unsigned short* __restrict__ Wf,
                                                    const float* __restrict__ dinv,
                                                    const float* __restrict__ b,
                                                    _Float16* __restrict__ Gout, int N) {
    __shared__ unsigned short Ahi[16 * 128];
    __shared__ unsigned short Alo[16 * 128];
    __shared__ float dinvS[16];
    int tid = threadIdx.x;
    int w = tid >> 6, lane = tid & 63, half = lane >> 5, l32 = lane & 31;
    long long base = (long long)blockIdx.x * 16;
    const half4* G4 = (const half4*)Gin;
#pragma unroll
    for (int rr = 0; rr < 2; ++rr) {
        int lrow = w + rr * 8;
        long long node = base + lrow;
        float4 acc = make_float4(0.f, 0.f, 0.f, 0.f);
        if (node < N) acc = gather_row8(rowptr, csr, G4, (int)node, l32, half);
        acc.x += __shfl_xor(acc.x, 32);
        acc.y += __shfl_xor(acc.y, 32);
        acc.z += __shfl_xor(acc.z, 32);
        acc.w += __shfl_xor(acc.w, 32);
        float4 h = make_float4(0.f, 0.f, 0.f, 0.f);
        float di = 0.f;
        if (node < N) {
            di = dinv[node];
            float4 bb = *(const float4*)&b[l32 * 4];
            h.x = fmaxf(fmaf(acc.x, di, bb.x), 0.f);
            h.y = fmaxf(fmaf(acc.y, di, bb.y), 0.f);
            h.z = fmaxf(fmaf(acc.z, di, bb.z), 0.f);
            h.w = fmaxf(fmaf(acc.w, di, bb.w), 0.f);
        }
        if (lane == 0) dinvS[lrow] = di;
        split_write(Ahi, Alo, h, lrow, l32, half);
    }
    __syncthreads();
    mfma_phase(Ahi, Alo, Wf, dinvS, Gout, base, N, w, lane);
}

// g4dec: h4 = relu(dinv*(gather G4) + b_hid); T3g = (h4 @ W_dec) * dinv  (wave/dst)
__global__ __launch_bounds__(256) void g4dec_kernel(const int* __restrict__ rowptr,
                                                    const int* __restrict__ csr,
                                                    const _Float16* __restrict__ Gin,
                                                    const float* __restrict__ dinv,
                                                    const float* __restrict__ bh,
                                                    const float* __restrict__ Wdec,
                                                    float* __restrict__ T3g, int N) {
    __shared__ float Wd[384];
    int tid = threadIdx.x;
    for (int i = tid; i < 384; i += 256) Wd[i] = Wdec[i];
    __syncthreads();
    int wv = (int)(((long long)blockIdx.x * 256 + tid) >> 6);
    if (wv >= N) return;
    int lane = tid & 63, half = lane >> 5, l32 = lane & 31;
    float4 acc = gather_row16(rowptr, csr, (const half4*)Gin, wv, l32, half);
    acc.x += __shfl_xor(acc.x, 32);
    acc.y += __shfl_xor(acc.y, 32);
    acc.z += __shfl_xor(acc.z, 32);
    acc.w += __shfl_xor(acc.w, 32);
    float di = dinv[wv];
    float4 bb = *(const float4*)&bh[l32 * 4];
    float4 h;
    h.x = fmaxf(fmaf(acc.x, di, bb.x), 0.f);
    h.y = fmaxf(fmaf(acc.y, di, bb.y), 0.f);
    h.z = fmaxf(fmaf(acc.z, di, bb.z), 0.f);
    h.w = fmaxf(fmaf(acc.w, di, bb.w), 0.f);
    int c0 = l32 * 4;
    float p0 = h.x * Wd[c0 * 3 + 0] + h.y * Wd[(c0 + 1) * 3 + 0]
             + h.z * Wd[(c0 + 2) * 3 + 0] + h.w * Wd[(c0 + 3) * 3 + 0];
    float p1 = h.x * Wd[c0 * 3 + 1] + h.y * Wd[(c0 + 1) * 3 + 1]
             + h.z * Wd[(c0 + 2) * 3 + 1] + h.w * Wd[(c0 + 3) * 3 + 1];
    float p2 = h.x * Wd[c0 * 3 + 2] + h.y * Wd[(c0 + 1) * 3 + 2]
             + h.z * Wd[(c0 + 2) * 3 + 2] + h.w * Wd[(c0 + 3) * 3 + 2];
#pragma unroll
    for (int o = 1; o < 32; o <<= 1) {
        p0 += __shfl_xor(p0, o);
        p1 += __shfl_xor(p1, o);
        p2 += __shfl_xor(p2, o);
    }
    if (lane == 0) {
        T3g[(long long)wv * 3 + 0] = p0 * di;
        T3g[(long long)wv * 3 + 1] = p1 * di;
        T3g[(long long)wv * 3 + 2] = p2 * di;
    }
}

// decoder aggregation (3-wide), thread per dst: out = dinv*(sum + self) + b
__global__ void gather3_kernel(const int* __restrict__ rowptr, const int* __restrict__ csr,
                               const float* __restrict__ T3g, const float* __restrict__ dinv,
                               const float* __restrict__ b, float* __restrict__ out, int N) {
    int i = blockIdx.x * blockDim.x + threadIdx.x;
    if (i >= N) return;
    int s = rowptr[i], e = rowptr[i + 1];
    const float* ti = T3g + (long long)i * 3;
    float a0 = ti[0], a1 = ti[1], a2 = ti[2];   // self
    for (int j = s; j < e; ++j) {
        int src = csr[j];
        const float* ts = T3g + (long long)src * 3;
        a0 += ts[0]; a1 += ts[1]; a2 += ts[2];
    }
    float di = dinv[i];
    float* o = out + (long long)i * 3;
    o[0] = fmaf(a0, di, b[0]);
    o[1] = fmaf(a1, di, b[1]);
    o[2] = fmaf(a2, di, b[2]);
}

extern "C" void kernel_launch(void* const* d_in, const int* in_sizes, int n_in,
                              void* d_out, int out_size, void* d_ws, size_t ws_size,
                              hipStream_t stream) {
    const float* x     = (const float*)d_in[0];
    const void* eidx   = d_in[1];
    const float* W_enc = (const float*)d_in[2];
    const float* b_enc = (const float*)d_in[3];
    const float* W_hid = (const float*)d_in[4];
    const float* b_hid = (const float*)d_in[5];
    const float* W_dec = (const float*)d_in[6];
    const float* b_dec = (const float*)d_in[7];

    const int N = in_sizes[0] / 6;          // 100000
    const long long E = in_sizes[1] / 2;    // 1600000
    const int NBLK = (N + 255) / 256;       // 391 (<= 512 for scan2)

    char* ws = (char*)d_ws;
    size_t off = 0;
    auto alloc = [&](size_t bytes) { char* p = ws + off; off += (bytes + 255) & ~(size_t)255; return p; };
    int*            flag   = (int*)alloc(4);
    float*          dinv   = (float*)alloc((size_t)N * 4);
    int*            cnt    = (int*)alloc((size_t)N * 4);
    int*            rowptr = (int*)alloc(((size_t)N + 1) * 4);
    int*            bsum   = (int*)alloc(2048 * 4);
    unsigned short* Wf     = (unsigned short*)alloc(2 * 16384 * 2);
    int*            csr    = (int*)alloc((size_t)E * 4);
    int*            rank   = (int*)alloc((size_t)E * 4);
    float*          aggV   = (float*)alloc((size_t)N * 6 * 4);      // enc agg; reused as T3g
    _Float16*       G1     = (_Float16*)alloc((size_t)N * HID * 2); // fp16 message planes
    _Float16*       G2     = (_Float16*)alloc((size_t)N * HID * 2);

    detect_kernel<<<1, 64, 0, stream>>>((const unsigned int*)eidx, E * 2, flag);

    // CSR build: rank pass -> dinv -> scan -> non-atomic fill
    hipMemsetAsync(cnt, 0, (size_t)N * 4, stream);
    rank_kernel<<<(int)((E + 255) / 256), 256, 0, stream>>>(eidx, E, flag, cnt, rank);
    dinv_kernel<<<NBLK, 256, 0, stream>>>(cnt, dinv, N);
    scan1_kernel<<<NBLK, 256, 0, stream>>>(cnt, rowptr, bsum, N);
    scan2_kernel<<<1, 512, 0, stream>>>(bsum, NBLK);
    scan3_kernel<<<NBLK, 256, 0, stream>>>(rowptr, bsum, N, E);
    fill2_kernel<<<(int)((E + 255) / 256), 256, 0, stream>>>(eidx, E, flag, rowptr, rank, csr);

    // W_hid fragment prep
    wprep_kernel<<<64, 256, 0, stream>>>(W_hid, Wf);

    // encoder: aggregate x, then fused enc-matmul + gemm1 -> G1
    gather6_kernel<<<NBLK, 256, 0, stream>>>(rowptr, csr, x, dinv, aggV, N);
    const int FGRID = (N + 15) / 16;
    encF_kernel<<<FGRID, 512, 0, stream>>>(aggV, W_enc, b_enc, Wf, dinv, G1, N);

    // 3 fused hidden steps: gather+relu+gemm
    fused_kernel<<<FGRID, 512, 0, stream>>>(rowptr, csr, G1, Wf, dinv, b_hid, G2, N);
    fused_kernel<<<FGRID, 512, 0, stream>>>(rowptr, csr, G2, Wf, dinv, b_hid, G1, N);
    fused_kernel<<<FGRID, 512, 0, stream>>>(rowptr, csr, G1, Wf, dinv, b_hid, G2, N);

    // 4th gather fused with decoder matmul -> T3g (aggV), then 3-wide aggregate
    g4dec_kernel<<<(N + 3) / 4, 256, 0, stream>>>(rowptr, csr, G2, dinv, b_hid, W_dec, aggV, N);
    gather3_kernel<<<NBLK, 256, 0, stream>>>(rowptr, csr, aggV, dinv, b_dec, (float*)d_out, N);
}

// Round 7
// 489.918 us; speedup vs baseline: 24.1583x; 1.0280x over previous
//
#include <hip/hip_runtime.h>

// MeshGNN: 6-layer GCN on 100k nodes / 1.6M edges, HIDDEN=128.
// Round 7: fused gather -> quarter-split (16 lanes/row x 16B half8 loads,
// 4 srcs in parallel, unroll 4 => 64B in flight/lane, half the VMEM instrs).
// detect parallelized; dinv folded into scan1; rowptr[N]=E folded into scan2.

#define HID 128

typedef __attribute__((ext_vector_type(4))) float f32x4;
typedef __attribute__((ext_vector_type(8))) short bf16x8;
typedef __attribute__((ext_vector_type(4))) _Float16 half4;
typedef __attribute__((ext_vector_type(8))) _Float16 half8;

__device__ __forceinline__ long long ld_idx(const void* p, long long i, int is64) {
    if (is64) return ((const long long*)p)[i];
    return (long long)((const int*)p)[i];
}

__device__ __forceinline__ unsigned short f2bf(float v) {
    unsigned u = __float_as_uint(v);
    unsigned r = (u + 0x7fffu + ((u >> 16) & 1u)) >> 16;
    return (unsigned short)r;
}
__device__ __forceinline__ float bf2f(unsigned short h) {
    return __uint_as_float(((unsigned)h) << 16);
}

// Probe int64 vs int32 edge layout (parallel: 64 lanes x 2 odd words each).
__global__ void detect_kernel(const unsigned int* e, long long nwords, int* flag) {
    int t = threadIdx.x;
    unsigned v = 0;
    long long i0 = 1 + 2 * (long long)t;
    long long i1 = 1 + 2 * (long long)(t + 64);
    if (i0 < nwords && i0 < 256) v |= e[i0];
    if (i1 < nwords && i1 < 256) v |= e[i1];
    int any = __any(v != 0u);
    if (t == 0) *flag = any ? 0 : 1;
}

// pass A: histogram + per-edge rank (single atomic pass)
__global__ void rank_kernel(const void* eidx, long long E, const int* flag,
                            int* __restrict__ cnt, int* __restrict__ rank) {
    long long i = (long long)blockIdx.x * blockDim.x + threadIdx.x;
    if (i >= E) return;
    int is64 = *flag;
    int d = (int)ld_idx(eidx, E + i, is64);
    rank[i] = atomicAdd(&cnt[d], 1);
}

// exclusive scan of cnt[N] -> rowptr[N]; also emits dinv = rsqrt(cnt+1)
__global__ void scan1_kernel(const int* cnt, int* rowptr, int* bsum, float* dinv, int N) {
    __shared__ int s[256];
    int i = blockIdx.x * 256 + threadIdx.x;
    int v = (i < N) ? cnt[i] : 0;
    if (i < N) dinv[i] = rsqrtf((float)v + 1.0f);
    s[threadIdx.x] = v;
    __syncthreads();
    for (int off = 1; off < 256; off <<= 1) {
        int t = (threadIdx.x >= off) ? s[threadIdx.x - off] : 0;
        __syncthreads();
        s[threadIdx.x] += t;
        __syncthreads();
    }
    if (i < N) rowptr[i] = s[threadIdx.x] - v;   // exclusive
    if (threadIdx.x == 255) bsum[blockIdx.x] = s[255];
}

__global__ void scan2_kernel(int* bsum, int nb, int* rowptrN, long long E) {
    __shared__ int s[512];
    int t = threadIdx.x;
    int v = (t < nb) ? bsum[t] : 0;
    s[t] = v;
    __syncthreads();
    for (int off = 1; off < 512; off <<= 1) {
        int u = (t >= off) ? s[t - off] : 0;
        __syncthreads();
        s[t] += u;
        __syncthreads();
    }
    if (t < nb) bsum[t] = s[t] - v;
    if (t == 0) *rowptrN = (int)E;
}

__global__ void scan3_kernel(int* rowptr, const int* bsum, int N) {
    int i = blockIdx.x * 256 + threadIdx.x;
    if (i < N) rowptr[i] += bsum[blockIdx.x];
}

// pass B: scatter src into CSR slot (no atomics)
__global__ void fill2_kernel(const void* eidx, long long E, const int* flag,
                             const int* __restrict__ rowptr, const int* __restrict__ rank,
                             int* __restrict__ csr) {
    long long i = (long long)blockIdx.x * blockDim.x + threadIdx.x;
    if (i >= E) return;
    int is64 = *flag;
    int s = (int)ld_idx(eidx, i, is64);
    int d = (int)ld_idx(eidx, E + i, is64);
    csr[rowptr[d] + rank[i]] = s;
}

// encoder aggregation (6-wide), thread per dst
__global__ void gather6_kernel(const int* __restrict__ rowptr, const int* __restrict__ csr,
                               const float* __restrict__ x, const float* __restrict__ dinv,
                               float* __restrict__ aggV, int N) {
    int i = blockIdx.x * blockDim.x + threadIdx.x;
    if (i >= N) return;
    int s = rowptr[i], e = rowptr[i + 1];
    float di = dinv[i];
    const float* xi = x + (long long)i * 6;
    float a0 = xi[0] * di, a1 = xi[1] * di, a2 = xi[2] * di;
    float a3 = xi[3] * di, a4 = xi[4] * di, a5 = xi[5] * di;
    for (int j = s; j < e; ++j) {
        int src = csr[j];
        float ds = dinv[src];
        const float* xs = x + (long long)src * 6;
        a0 += xs[0] * ds; a1 += xs[1] * ds; a2 += xs[2] * ds;
        a3 += xs[3] * ds; a4 += xs[4] * ds; a5 += xs[5] * ds;
    }
    float* o = aggV + (long long)i * 6;
    o[0] = a0 * di; o[1] = a1 * di; o[2] = a2 * di;
    o[3] = a3 * di; o[4] = a4 * di; o[5] = a5 * di;
}

// W_hid -> fragment-ordered split-bf16 (unchanged layout from r3-r6)
__global__ void wprep_kernel(const float* __restrict__ W, unsigned short* __restrict__ Wf) {
    int idx = blockIdx.x * 256 + threadIdx.x;
    if (idx >= 16384) return;
    int j = idx & 7;
    int lane = (idx >> 3) & 63;
    int ks = (idx >> 9) & 3;
    int nt = idx >> 11;
    int c = (nt << 4) + (lane & 15);
    int k = (ks << 5) + ((lane >> 4) << 3) + j;
    float v = W[k * 128 + c];
    unsigned short hi = f2bf(v);
    unsigned short lo = f2bf(v - bf2f(hi));
    Wf[idx] = hi;
    Wf[idx + 16384] = lo;
}

// ---- shared device pieces ----

// 16-row-unrolled parity gather (used by g4dec; unchanged from r6)
__device__ __forceinline__ float4 gather_row16(const int* __restrict__ rowptr,
                                               const int* __restrict__ csr,
                                               const half4* __restrict__ G4,
                                               int wv, int l32, int half) {
    int s = rowptr[wv], e = rowptr[wv + 1];
    int deg = e - s;
    float4 acc = make_float4(0.f, 0.f, 0.f, 0.f);
    if (half == 0) {
        half4 sv = G4[(long long)wv * 32 + l32];
        acc.x = (float)sv.x; acc.y = (float)sv.y; acc.z = (float)sv.z; acc.w = (float)sv.w;
    }
    const int* cp = csr + s + half;
    int n16 = deg >> 4;
    for (int it = 0; it < n16; ++it) {
        int i0 = cp[0], i1 = cp[2], i2 = cp[4], i3 = cp[6];
        int i4 = cp[8], i5 = cp[10], i6 = cp[12], i7 = cp[14];
        half4 v0 = G4[(long long)i0 * 32 + l32];
        half4 v1 = G4[(long long)i1 * 32 + l32];
        half4 v2 = G4[(long long)i2 * 32 + l32];
        half4 v3 = G4[(long long)i3 * 32 + l32];
        half4 v4 = G4[(long long)i4 * 32 + l32];
        half4 v5 = G4[(long long)i5 * 32 + l32];
        half4 v6 = G4[(long long)i6 * 32 + l32];
        half4 v7 = G4[(long long)i7 * 32 + l32];
        acc.x += ((float)v0.x + (float)v1.x) + ((float)v2.x + (float)v3.x)
               + ((float)v4.x + (float)v5.x) + ((float)v6.x + (float)v7.x);
        acc.y += ((float)v0.y + (float)v1.y) + ((float)v2.y + (float)v3.y)
               + ((float)v4.y + (float)v5.y) + ((float)v6.y + (float)v7.y);
        acc.z += ((float)v0.z + (float)v1.z) + ((float)v2.z + (float)v3.z)
               + ((float)v4.z + (float)v5.z) + ((float)v6.z + (float)v7.z);
        acc.w += ((float)v0.w + (float)v1.w) + ((float)v2.w + (float)v3.w)
               + ((float)v4.w + (float)v5.w) + ((float)v6.w + (float)v7.w);
        cp += 16;
    }
    if (deg & 8) {
        int i0 = cp[0], i1 = cp[2], i2 = cp[4], i3 = cp[6];
        half4 v0 = G4[(long long)i0 * 32 + l32];
        half4 v1 = G4[(long long)i1 * 32 + l32];
        half4 v2 = G4[(long long)i2 * 32 + l32];
        half4 v3 = G4[(long long)i3 * 32 + l32];
        acc.x += (float)v0.x + (float)v1.x + (float)v2.x + (float)v3.x;
        acc.y += (float)v0.y + (float)v1.y + (float)v2.y + (float)v3.y;
        acc.z += (float)v0.z + (float)v1.z + (float)v2.z + (float)v3.z;
        acc.w += (float)v0.w + (float)v1.w + (float)v2.w + (float)v3.w;
    }
    for (int j = s + (deg & ~7) + half; j < e; j += 2) {
        int i0 = csr[j];
        half4 v = G4[(long long)i0 * 32 + l32];
        acc.x += (float)v.x; acc.y += (float)v.y; acc.z += (float)v.z; acc.w += (float)v.w;
    }
    return acc;
}

// MFMA phase: 16 rows (LDS split-bf16) x W_hid-fragments -> Gout fp16, x dinv[row]
__device__ __forceinline__ void mfma_phase(const unsigned short* Ahi, const unsigned short* Alo,
                                           const unsigned short* __restrict__ Wf,
                                           const float* dinvS, _Float16* __restrict__ Gout,
                                           long long base, int N, int w, int lane) {
    int arow = lane & 15;
    int abase = arow * 128;
    f32x4 acc = {};
    const bf16x8* Bf = (const bf16x8*)Wf;
#pragma unroll
    for (int ks = 0; ks < 4; ++ks) {
        int slot = (ks << 2) + (lane >> 4);
        int aoff = abase + ((slot ^ (arow & 7)) << 3);
        bf16x8 ah = *(const bf16x8*)&Ahi[aoff];
        bf16x8 al = *(const bf16x8*)&Alo[aoff];
        int g = (((w << 2) + ks) << 6) + lane;
        bf16x8 bh = Bf[g];
        bf16x8 bl = Bf[g + 2048];
        acc = __builtin_amdgcn_mfma_f32_16x16x32_bf16(ah, bh, acc, 0, 0, 0);
        acc = __builtin_amdgcn_mfma_f32_16x16x32_bf16(ah, bl, acc, 0, 0, 0);
        acc = __builtin_amdgcn_mfma_f32_16x16x32_bf16(al, bh, acc, 0, 0, 0);
    }
    int rbase = (lane >> 4) << 2;
    int col = (w << 4) + (lane & 15);
#pragma unroll
    for (int r = 0; r < 4; ++r) {
        int lrow = rbase + r;
        long long grow = base + lrow;
        if (grow < N) Gout[grow * HID + col] = (_Float16)(acc[r] * dinvS[lrow]);
    }
}

// old parity split-write (8B per half), used by encF
__device__ __forceinline__ void split_write(unsigned short* Ahi, unsigned short* Alo,
                                            float4 h, int lrow, int l32, int half) {
    unsigned short h0 = f2bf(h.x), h1 = f2bf(h.y), h2 = f2bf(h.z), h3 = f2bf(h.w);
    int slot = l32 >> 1;
    int off = lrow * 128 + (((slot ^ (lrow & 7)) << 3) | ((l32 & 1) << 2));
    if (half == 0) {
        *(uint2*)&Ahi[off] = make_uint2((unsigned)h0 | ((unsigned)h1 << 16),
                                        (unsigned)h2 | ((unsigned)h3 << 16));
    } else {
        unsigned short l0 = f2bf(h.x - bf2f(h0));
        unsigned short l1 = f2bf(h.y - bf2f(h1));
        unsigned short l2 = f2bf(h.z - bf2f(h2));
        unsigned short l3 = f2bf(h.w - bf2f(h3));
        *(uint2*)&Alo[off] = make_uint2((unsigned)l0 | ((unsigned)l1 << 16),
                                        (unsigned)l2 | ((unsigned)l3 << 16));
    }
}

// encF: h0 = relu(aggV @ W_enc + b_enc); G1 = (h0 @ W_hid) * dinv  (16 nodes/block)
__global__ __launch_bounds__(512) void encF_kernel(const float* __restrict__ aggV,
                                                   const float* __restrict__ Wenc,
                                                   const float* __restrict__ benc,
                                                   const unsigned short* __restrict__ Wf,
                                                   const float* __restrict__ dinv,
                                                   _Float16* __restrict__ Gout, int N) {
    __shared__ unsigned short Ahi[16 * 128];
    __shared__ unsigned short Alo[16 * 128];
    __shared__ float WencS[6 * 128];
    __shared__ float dinvS[16];
    int tid = threadIdx.x;
    for (int i = tid; i < 768; i += 512) WencS[i] = Wenc[i];
    __syncthreads();
    int w = tid >> 6, lane = tid & 63, half = lane >> 5, l32 = lane & 31;
    long long base = (long long)blockIdx.x * 16;
#pragma unroll
    for (int rr = 0; rr < 2; ++rr) {
        int lrow = w + rr * 8;
        long long node = base + lrow;
        float4 h = make_float4(0.f, 0.f, 0.f, 0.f);
        float di = 0.f;
        if (node < N) {
            di = dinv[node];
            const float* av = aggV + node * 6;
            float a0 = av[0], a1 = av[1], a2 = av[2], a3 = av[3], a4 = av[4], a5 = av[5];
            float4 bb = *(const float4*)&benc[l32 * 4];
            int c = l32 * 4;
            h = bb;
#define EK(AK, K)                                                   \
            h.x = fmaf(AK, WencS[(K) * 128 + c + 0], h.x);          \
            h.y = fmaf(AK, WencS[(K) * 128 + c + 1], h.y);          \
            h.z = fmaf(AK, WencS[(K) * 128 + c + 2], h.z);          \
            h.w = fmaf(AK, WencS[(K) * 128 + c + 3], h.w);
            EK(a0, 0) EK(a1, 1) EK(a2, 2) EK(a3, 3) EK(a4, 4) EK(a5, 5)
#undef EK
            h.x = fmaxf(h.x, 0.f); h.y = fmaxf(h.y, 0.f);
            h.z = fmaxf(h.z, 0.f); h.w = fmaxf(h.w, 0.f);
        }
        if (lane == 0) dinvS[lrow] = di;
        split_write(Ahi, Alo, h, lrow, l32, half);
    }
    __syncthreads();
    mfma_phase(Ahi, Alo, Wf, dinvS, Gout, base, N, w, lane);
}

// fused hidden step, quarter-split gather:
// lane = (q = lane>>4, l16 = lane&15); lane owns cols [8*l16, 8*l16+8) of srcs
// with index ≡ q (mod 4); 16B half8 loads, unroll 4 (64B in flight per lane).
__global__ __launch_bounds__(512) void fused_kernel(const int* __restrict__ rowptr,
                                                    const int* __restrict__ csr,
                                                    const _Float16* __restrict__ Gin,
                                                    const unsigned short* __restrict__ Wf,
                                                    const float* __restrict__ dinv,
                                                    const float* __restrict__ b,
                                                    _Float16* __restrict__ Gout, int N) {
    __shared__ unsigned short Ahi[16 * 128];
    __shared__ unsigned short Alo[16 * 128];
    __shared__ float dinvS[16];
    int tid = threadIdx.x;
    int w = tid >> 6, lane = tid & 63, q = lane >> 4, l16 = lane & 15;
    long long base = (long long)blockIdx.x * 16;
    const half8* G8 = (const half8*)Gin;    // row = 16 half8s
#pragma unroll
    for (int rr = 0; rr < 2; ++rr) {
        int lrow = w + rr * 8;
        long long node = base + lrow;
        float a0 = 0.f, a1 = 0.f, a2 = 0.f, a3 = 0.f;
        float a4 = 0.f, a5 = 0.f, a6 = 0.f, a7 = 0.f;
        if (node < N) {
            int s = rowptr[node], e = rowptr[node + 1];
            int deg = e - s;
            if (q == 0) {                    // self term on quarter 0
                half8 sv = G8[node * 16 + l16];
                a0 = (float)sv[0]; a1 = (float)sv[1]; a2 = (float)sv[2]; a3 = (float)sv[3];
                a4 = (float)sv[4]; a5 = (float)sv[5]; a6 = (float)sv[6]; a7 = (float)sv[7];
            }
            int n16 = deg >> 4;
            const int* cs = csr + s + q;
            for (int it = 0; it < n16; ++it) {
                int i0 = cs[0], i1 = cs[4], i2 = cs[8], i3 = cs[12];
                half8 v0 = G8[(long long)i0 * 16 + l16];
                half8 v1 = G8[(long long)i1 * 16 + l16];
                half8 v2 = G8[(long long)i2 * 16 + l16];
                half8 v3 = G8[(long long)i3 * 16 + l16];
                a0 += ((float)v0[0] + (float)v1[0]) + ((float)v2[0] + (float)v3[0]);
                a1 += ((float)v0[1] + (float)v1[1]) + ((float)v2[1] + (float)v3[1]);
                a2 += ((float)v0[2] + (float)v1[2]) + ((float)v2[2] + (float)v3[2]);
                a3 += ((float)v0[3] + (float)v1[3]) + ((float)v2[3] + (float)v3[3]);
                a4 += ((float)v0[4] + (float)v1[4]) + ((float)v2[4] + (float)v3[4]);
                a5 += ((float)v0[5] + (float)v1[5]) + ((float)v2[5] + (float)v3[5]);
                a6 += ((float)v0[6] + (float)v1[6]) + ((float)v2[6] + (float)v3[6]);
                a7 += ((float)v0[7] + (float)v1[7]) + ((float)v2[7] + (float)v3[7]);
                cs += 16;
            }
            for (int j = s + (deg & ~15) + q; j < e; j += 4) {   // tail, <=3 extra
                int i0 = csr[j];
                half8 v = G8[(long long)i0 * 16 + l16];
                a0 += (float)v[0]; a1 += (float)v[1]; a2 += (float)v[2]; a3 += (float)v[3];
                a4 += (float)v[4]; a5 += (float)v[5]; a6 += (float)v[6]; a7 += (float)v[7];
            }
        }
        // combine quarters (lanes l16, l16+16, l16+32, l16+48)
#define RED(A) A += __shfl_xor(A, 16); A += __shfl_xor(A, 32);
        RED(a0) RED(a1) RED(a2) RED(a3) RED(a4) RED(a5) RED(a6) RED(a7)
#undef RED
        float di = 0.f;
        unsigned short hb[8];
        if (node < N) {
            di = dinv[node];
            const float* bp = b + l16 * 8;
            a0 = fmaxf(fmaf(a0, di, bp[0]), 0.f);
            a1 = fmaxf(fmaf(a1, di, bp[1]), 0.f);
            a2 = fmaxf(fmaf(a2, di, bp[2]), 0.f);
            a3 = fmaxf(fmaf(a3, di, bp[3]), 0.f);
            a4 = fmaxf(fmaf(a4, di, bp[4]), 0.f);
            a5 = fmaxf(fmaf(a5, di, bp[5]), 0.f);
            a6 = fmaxf(fmaf(a6, di, bp[6]), 0.f);
            a7 = fmaxf(fmaf(a7, di, bp[7]), 0.f);
        } else {
            a0 = a1 = a2 = a3 = a4 = a5 = a6 = a7 = 0.f;
        }
        hb[0] = f2bf(a0); hb[1] = f2bf(a1); hb[2] = f2bf(a2); hb[3] = f2bf(a3);
        hb[4] = f2bf(a4); hb[5] = f2bf(a5); hb[6] = f2bf(a6); hb[7] = f2bf(a7);
        int off = lrow * 128 + ((l16 ^ (lrow & 7)) << 3);
        if (q == 0) {           // hi plane: 16B per lane
            uint4 pk;
            pk.x = (unsigned)hb[0] | ((unsigned)hb[1] << 16);
            pk.y = (unsigned)hb[2] | ((unsigned)hb[3] << 16);
            pk.z = (unsigned)hb[4] | ((unsigned)hb[5] << 16);
            pk.w = (unsigned)hb[6] | ((unsigned)hb[7] << 16);
            *(uint4*)&Ahi[off] = pk;
        } else if (q == 1) {    // lo plane
            unsigned short lb[8];
            lb[0] = f2bf(a0 - bf2f(hb[0])); lb[1] = f2bf(a1 - bf2f(hb[1]));
            lb[2] = f2bf(a2 - bf2f(hb[2])); lb[3] = f2bf(a3 - bf2f(hb[3]));
            lb[4] = f2bf(a4 - bf2f(hb[4])); lb[5] = f2bf(a5 - bf2f(hb[5]));
            lb[6] = f2bf(a6 - bf2f(hb[6])); lb[7] = f2bf(a7 - bf2f(hb[7]));
            uint4 pk;
            pk.x = (unsigned)lb[0] | ((unsigned)lb[1] << 16);
            pk.y = (unsigned)lb[2] | ((unsigned)lb[3] << 16);
            pk.z = (unsigned)lb[4] | ((unsigned)lb[5] << 16);
            pk.w = (unsigned)lb[6] | ((unsigned)lb[7] << 16);
            *(uint4*)&Alo[off] = pk;
        }
        if (lane == 0) dinvS[lrow] = di;
    }
    __syncthreads();
    mfma_phase(Ahi, Alo, Wf, dinvS, Gout, base, N, w, lane);
}

// g4dec: h4 = relu(dinv*(gather G4) + b_hid); T3g = (h4 @ W_dec) * dinv  (wave/dst)
__global__ __launch_bounds__(256) void g4dec_kernel(const int* __restrict__ rowptr,
                                                    const int* __restrict__ csr,
                                                    const _Float16* __restrict__ Gin,
                                                    const float* __restrict__ dinv,
                                                    const float* __restrict__ bh,
                                                    const float* __restrict__ Wdec,
                                                    float* __restrict__ T3g, int N) {
    __shared__ float Wd[384];
    int tid = threadIdx.x;
    for (int i = tid; i < 384; i += 256) Wd[i] = Wdec[i];
    __syncthreads();
    int wv = (int)(((long long)blockIdx.x * 256 + tid) >> 6);
    if (wv >= N) return;
    int lane = tid & 63, half = lane >> 5, l32 = lane & 31;
    float4 acc = gather_row16(rowptr, csr, (const half4*)Gin, wv, l32, half);
    acc.x += __shfl_xor(acc.x, 32);
    acc.y += __shfl_xor(acc.y, 32);
    acc.z += __shfl_xor(acc.z, 32);
    acc.w += __shfl_xor(acc.w, 32);
    float di = dinv[wv];
    float4 bb = *(const float4*)&bh[l32 * 4];
    float4 h;
    h.x = fmaxf(fmaf(acc.x, di, bb.x), 0.f);
    h.y = fmaxf(fmaf(acc.y, di, bb.y), 0.f);
    h.z = fmaxf(fmaf(acc.z, di, bb.z), 0.f);
    h.w = fmaxf(fmaf(acc.w, di, bb.w), 0.f);
    int c0 = l32 * 4;
    float p0 = h.x * Wd[c0 * 3 + 0] + h.y * Wd[(c0 + 1) * 3 + 0]
             + h.z * Wd[(c0 + 2) * 3 + 0] + h.w * Wd[(c0 + 3) * 3 + 0];
    float p1 = h.x * Wd[c0 * 3 + 1] + h.y * Wd[(c0 + 1) * 3 + 1]
             + h.z * Wd[(c0 + 2) * 3 + 1] + h.w * Wd[(c0 + 3) * 3 + 1];
    float p2 = h.x * Wd[c0 * 3 + 2] + h.y * Wd[(c0 + 1) * 3 + 2]
             + h.z * Wd[(c0 + 2) * 3 + 2] + h.w * Wd[(c0 + 3) * 3 + 2];
#pragma unroll
    for (int o = 1; o < 32; o <<= 1) {
        p0 += __shfl_xor(p0, o);
        p1 += __shfl_xor(p1, o);
        p2 += __shfl_xor(p2, o);
    }
    if (lane == 0) {
        T3g[(long long)wv * 3 + 0] = p0 * di;
        T3g[(long long)wv * 3 + 1] = p1 * di;
        T3g[(long long)wv * 3 + 2] = p2 * di;
    }
}

// decoder aggregation (3-wide), thread per dst: out = dinv*(sum + self) + b
__global__ void gather3_kernel(const int* __restrict__ rowptr, const int* __restrict__ csr,
                               const float* __restrict__ T3g, const float* __restrict__ dinv,
                               const float* __restrict__ b, float* __restrict__ out, int N) {
    int i = blockIdx.x * blockDim.x + threadIdx.x;
    if (i >= N) return;
    int s = rowptr[i], e = rowptr[i + 1];
    const float* ti = T3g + (long long)i * 3;
    float a0 = ti[0], a1 = ti[1], a2 = ti[2];   // self
    for (int j = s; j < e; ++j) {
        int src = csr[j];
        const float* ts = T3g + (long long)src * 3;
        a0 += ts[0]; a1 += ts[1]; a2 += ts[2];
    }
    float di = dinv[i];
    float* o = out + (long long)i * 3;
    o[0] = fmaf(a0, di, b[0]);
    o[1] = fmaf(a1, di, b[1]);
    o[2] = fmaf(a2, di, b[2]);
}

extern "C" void kernel_launch(void* const* d_in, const int* in_sizes, int n_in,
                              void* d_out, int out_size, void* d_ws, size_t ws_size,
                              hipStream_t stream) {
    const float* x     = (const float*)d_in[0];
    const void* eidx   = d_in[1];
    const float* W_enc = (const float*)d_in[2];
    const float* b_enc = (const float*)d_in[3];
    const float* W_hid = (const float*)d_in[4];
    const float* b_hid = (const float*)d_in[5];
    const float* W_dec = (const float*)d_in[6];
    const float* b_dec = (const float*)d_in[7];

    const int N = in_sizes[0] / 6;          // 100000
    const long long E = in_sizes[1] / 2;    // 1600000
    const int NBLK = (N + 255) / 256;       // 391 (<= 512 for scan2)

    char* ws = (char*)d_ws;
    size_t off = 0;
    auto alloc = [&](size_t bytes) { char* p = ws + off; off += (bytes + 255) & ~(size_t)255; return p; };
    int*            flag   = (int*)alloc(4);
    float*          dinv   = (float*)alloc((size_t)N * 4);
    int*            cnt    = (int*)alloc((size_t)N * 4);
    int*            rowptr = (int*)alloc(((size_t)N + 1) * 4);
    int*            bsum   = (int*)alloc(2048 * 4);
    unsigned short* Wf     = (unsigned short*)alloc(2 * 16384 * 2);
    int*            csr    = (int*)alloc((size_t)E * 4);
    int*            rank   = (int*)alloc((size_t)E * 4);
    float*          aggV   = (float*)alloc((size_t)N * 6 * 4);      // enc agg; reused as T3g
    _Float16*       G1     = (_Float16*)alloc((size_t)N * HID * 2); // fp16 message planes
    _Float16*       G2     = (_Float16*)alloc((size_t)N * HID * 2);

    detect_kernel<<<1, 64, 0, stream>>>((const unsigned int*)eidx, E * 2, flag);

    // CSR build: rank pass -> scan (emits dinv) -> non-atomic fill
    hipMemsetAsync(cnt, 0, (size_t)N * 4, stream);
    rank_kernel<<<(int)((E + 255) / 256), 256, 0, stream>>>(eidx, E, flag, cnt, rank);
    scan1_kernel<<<NBLK, 256, 0, stream>>>(cnt, rowptr, bsum, dinv, N);
    scan2_kernel<<<1, 512, 0, stream>>>(bsum, NBLK, rowptr + N, E);
    scan3_kernel<<<NBLK, 256, 0, stream>>>(rowptr, bsum, N);
    fill2_kernel<<<(int)((E + 255) / 256), 256, 0, stream>>>(eidx, E, flag, rowptr, rank, csr);

    // W_hid fragment prep
    wprep_kernel<<<64, 256, 0, stream>>>(W_hid, Wf);

    // encoder: aggregate x, then fused enc-matmul + gemm1 -> G1
    gather6_kernel<<<NBLK, 256, 0, stream>>>(rowptr, csr, x, dinv, aggV, N);
    const int FGRID = (N + 15) / 16;
    encF_kernel<<<FGRID, 512, 0, stream>>>(aggV, W_enc, b_enc, Wf, dinv, G1, N);

    // 3 fused hidden steps: gather+relu+gemm
    fused_kernel<<<FGRID, 512, 0, stream>>>(rowptr, csr, G1, Wf, dinv, b_hid, G2, N);
    fused_kernel<<<FGRID, 512, 0, stream>>>(rowptr, csr, G2, Wf, dinv, b_hid, G1, N);
    fused_kernel<<<FGRID, 512, 0, stream>>>(rowptr, csr, G1, Wf, dinv, b_hid, G2, N);

    // 4th gather fused with decoder matmul -> T3g (aggV), then 3-wide aggregate
    g4dec_kernel<<<(N + 3) / 4, 256, 0, stream>>>(rowptr, csr, G2, dinv, b_hid, W_dec, aggV, N);
    gather3_kernel<<<NBLK, 256, 0, stream>>>(rowptr, csr, aggV, dinv, b_dec, (float*)d_out, N);
}